// Round 10
// baseline (604.898 us; speedup 1.0000x reference)
//
#include <hip/hip_runtime.h>

#define NN 50000
#define EE 1600000
#define DD 128
#define CC 10
#define LLAY 4
#define GG 512
#define GD (GG*DD)
#define NB 196           // ceil(NN/256) coarse buckets
#define BK_EDGES 1024    // edges per binA block (1563 blocks)
#define BUCKCAP 16000    // fixed binned region per bucket (expected 8192, >8 sigma safe)
#define NSUB 16          // src sub-tiles per node list (sorted gather window)
#define SUBW 3125        // 50000/16
#define WPAD 136         // Wl row stride in shorts (272B = 17 uint4: 2-way banks = free)

static constexpr float BN_EPS = 1e-5f;
static constexpr float INV_N = 1.0f / (float)NN;

typedef __bf16 bf16x8 __attribute__((ext_vector_type(8)));
typedef float f32x4 __attribute__((ext_vector_type(4)));

static __device__ __forceinline__ float bflo(unsigned u){ return __uint_as_float(u << 16); }
static __device__ __forceinline__ float bfhi(unsigned u){ return __uint_as_float(u & 0xffff0000u); }
static __device__ __forceinline__ unsigned short f2bf(float f){
    unsigned u = __float_as_uint(f);
    return (unsigned short)((u + 0x7fffu + ((u >> 16) & 1u)) >> 16);   // RNE
}
static __device__ __forceinline__ unsigned packbf(float a, float b){
    return (unsigned)f2bf(a) | ((unsigned)f2bf(b) << 16);
}
// order-preserving float<->uint for atomicMax on signed floats
static __device__ __forceinline__ unsigned encf(float f){
    unsigned b = __float_as_uint(f);
    return (b & 0x80000000u) ? ~b : (b | 0x80000000u);
}
static __device__ __forceinline__ float decf(unsigned e){
    unsigned b = (e & 0x80000000u) ? (e ^ 0x80000000u) : ~e;
    return __uint_as_float(b);
}
static __device__ __forceinline__ bf16x8 ldfrag(const unsigned short* p){
    union { uint4 u; bf16x8 b; } t; t.u = *(const uint4*)p; return t.b;
}
static __device__ __forceinline__ bf16x8 asfrag(uint4 u){
    union { uint4 u; bf16x8 b; } t; t.u = u; return t.b;
}

// ---------------- setup kernels ----------------

__global__ void zero_k(int* p, int n){
    int i = blockIdx.x * 256 + threadIdx.x;
    if (i < n) p[i] = 0;
}

// all 8 weight matrices -> bf16 W^T [j][k] in ws
__global__ void wprep_k(const float* __restrict__ W1, const float* __restrict__ W2,
                        unsigned short* __restrict__ Wtall){
    int idx = blockIdx.x * 256 + threadIdx.x;         // < 8*16384
    int mat = idx >> 14; int rr = idx & 16383;
    int k = rr >> 7; int j = rr & 127;
    const float* Wsrc = (mat < 4) ? (W1 + mat * 16384) : (W2 + (mat - 4) * 16384);
    Wtall[mat * 16384 + j * 128 + k] = f2bf(Wsrc[k * 128 + j]);
}

// graph boundaries via binary search on sorted batch
__global__ void gsearch_k(const int* __restrict__ batch, int* __restrict__ gstart){
    int g = blockIdx.x * 256 + threadIdx.x;
    if (g <= GG){
        int lo = 0, hi = NN;
        while (lo < hi){ int mid = (lo + hi) >> 1; if (batch[mid] < g) lo = mid + 1; else hi = mid; }
        gstart[g] = lo;
    }
}

// Pass A v3 (fixed): bin edges into NB bucket regions with COALESCED writes.
// Block-local counting sort: per-bucket count -> scan -> scatter into a sorted
// LDS stage -> write out in bucket order. FIX vs r9: output address includes the
// bucket region base lo*BUCKCAP (r9 omitted it -> corrupted binned -> crash).
__global__ __launch_bounds__(256) void binA_k(const int* __restrict__ srcA,
                                              const int* __restrict__ dstA,
                                              int* __restrict__ bucketCur,
                                              unsigned* __restrict__ binned){
    __shared__ int cnt[256];           // per-bucket counts (NB <= 256)
    __shared__ int lb[256];            // scan buffer -> local exclusive base
    __shared__ int bas[NB];            // global base per bucket
    __shared__ int off[NB];            // running offset for LDS scatter
    __shared__ unsigned stage[BK_EDGES];
    __shared__ int tots;
    int tid = threadIdx.x;
    cnt[tid] = 0;
    if (tid < NB) off[tid] = 0;
    __syncthreads();
    int e0 = blockIdx.x * BK_EDGES;
    int myB[4]; unsigned myVal[4];
    #pragma unroll
    for (int k = 0; k < 4; k++){
        int e = e0 + tid + k * 256;
        bool v = (e < EE);
        int d = v ? dstA[e] : -1;
        int s = v ? srcA[e] : 0;
        myB[k] = v ? (d >> 8) : -1;
        myVal[k] = (unsigned)s | ((unsigned)(d & 255) << 17);   // src<2^17
        if (v) atomicAdd(&cnt[d >> 8], 1);
    }
    __syncthreads();
    int v = cnt[tid];
    lb[tid] = v; __syncthreads();
    for (int o = 1; o < 256; o <<= 1){                 // Hillis-Steele inclusive scan
        int x = 0; if (tid >= o) x = lb[tid - o];
        __syncthreads(); lb[tid] += x; __syncthreads();
    }
    int incl = lb[tid];
    if (tid == 255) tots = incl;
    __syncthreads();
    lb[tid] = incl - v;                                // exclusive base
    if (tid < NB && v > 0) bas[tid] = atomicAdd(&bucketCur[tid], v);
    __syncthreads();
    #pragma unroll
    for (int k = 0; k < 4; k++){
        int b = myB[k];
        if (b >= 0){
            int p = lb[b] + atomicAdd(&off[b], 1);
            stage[p] = myVal[k];
        }
    }
    __syncthreads();
    int tot = tots;
    for (int i = tid; i < tot; i += 256){
        // largest b with lb[b] <= i  (returned bucket is always non-empty)
        int lo = 0, hi = NB - 1;
        while (lo < hi){
            int mid = (lo + hi + 1) >> 1;
            if (lb[mid] <= i) lo = mid; else hi = mid - 1;
        }
        binned[lo * BUCKCAP + bas[lo] + (i - lb[lo])] = stage[i];
    }
}

// scan bucket counts (post-binA) -> bucketBase; terminal rp entry
__global__ __launch_bounds__(256) void bscan_k(const int* __restrict__ bucketCur,
                                               int* __restrict__ bucketBase,
                                               int* __restrict__ rp){
    __shared__ int lds[256];
    int t = threadIdx.x;
    int v = (t < NB) ? bucketCur[t] : 0;
    lds[t] = v; __syncthreads();
    for (int o = 1; o < 256; o <<= 1){
        int xv = 0; if (t >= o) xv = lds[t - o];
        __syncthreads(); lds[t] += xv; __syncthreads();
    }
    int excl = lds[t] - v;
    if (t < NB) bucketBase[t] = excl;
    if (t == 0){ bucketBase[NB] = EE; rp[NN] = EE; }
}

// Pass B (1024 thr): per-bucket (node, 16-subtile) counts -> rp + src-sorted placement.
__global__ __launch_bounds__(1024) void binB_k(const unsigned* __restrict__ binned,
                                               const int* __restrict__ bucketCur,
                                               const int* __restrict__ bucketBase,
                                               int* __restrict__ rp,
                                               int* __restrict__ ssort){
    __shared__ int c16[256 * NSUB];   // 16 KB
    __shared__ int b16[256 * NSUB];   // 16 KB
    __shared__ int nt[256];
    int b = blockIdx.x, tid = threadIdx.x;
    int nb0 = b * 256;
    int nmax = NN - nb0; if (nmax > 256) nmax = 256;
    for (int i = tid; i < 256 * NSUB; i += 1024) c16[i] = 0;
    __syncthreads();
    int cntb = bucketCur[b];
    int src0 = b * BUCKCAP;
    int base = bucketBase[b];
    for (int i = tid; i < cntb; i += 1024){
        unsigned u = binned[src0 + i];
        int src = (int)(u & 0x1FFFFu); int dl = (int)(u >> 17);
        atomicAdd(&c16[dl * NSUB + src / SUBW], 1);
    }
    __syncthreads();
    int cc[NSUB]; int tot = 0;
    if (tid < 256){
        #pragma unroll
        for (int k = 0; k < NSUB; k++){ cc[k] = c16[tid * NSUB + k]; tot += cc[k]; }
        nt[tid] = tot;
    }
    __syncthreads();
    for (int o = 1; o < 256; o <<= 1){
        int xv = 0;
        if (tid < 256 && tid >= o) xv = nt[tid - o];
        __syncthreads();
        if (tid < 256) nt[tid] += xv;
        __syncthreads();
    }
    if (tid < 256){
        int p = base + nt[tid] - tot;
        if (tid < nmax) rp[nb0 + tid] = p;
        int run = p;
        #pragma unroll
        for (int k = 0; k < NSUB; k++){ b16[tid * NSUB + k] = run; run += cc[k]; }
    }
    __syncthreads();
    for (int i = tid; i < 256 * NSUB; i += 1024) c16[i] = 0;
    __syncthreads();
    for (int i = tid; i < cntb; i += 1024){
        unsigned u = binned[src0 + i];
        int src = (int)(u & 0x1FFFFu); int dl = (int)(u >> 17);
        int t = src / SUBW;
        int pos = b16[dl * NSUB + t] + atomicAdd(&c16[dl * NSUB + t], 1);
        ssort[pos] = src;
    }
}

// column absmax of x (for layer-0 int8 scales). nonneg floats: raw-bit atomicMax ok.
__global__ __launch_bounds__(256) void xmax_k(const float* __restrict__ x,
                                              unsigned* __restrict__ xmaxE){
    __shared__ float sm[256];
    int tid = threadIdx.x;
    int col = tid & 127, rh = tid >> 7;
    float m = 0.f;
    for (int r = blockIdx.x * 2 + rh; r < NN; r += 1024)
        m = fmaxf(m, fabsf(x[r * 128 + col]));
    sm[tid] = m; __syncthreads();
    if (tid < 128){
        m = fmaxf(sm[tid], sm[tid + 128]);
        atomicMax(&xmaxE[col], __float_as_uint(m));
    }
}

// layer-0 scales: qD[c] = xmax/127 (decode step), qR[c] = 127/xmax (encode)
__global__ void qx_k(const unsigned* __restrict__ xmaxE,
                     float* __restrict__ qD, float* __restrict__ qR){
    int c = threadIdx.x;   // 128 threads
    float m = __uint_as_float(xmaxE[c]);
    qD[c] = m * (1.f / 127.f);
    qR[c] = (m > 0.f) ? 127.f / m : 0.f;
}

// x (fp32) -> int8 codes (offset-128) only, fused with x-pooling.
__global__ __launch_bounds__(256) void convxpool_k(const float2* __restrict__ x2,
                                                   const int* __restrict__ gstart,
                                                   unsigned short* __restrict__ h8u,
                                                   const float* __restrict__ qR0,
                                                   float* __restrict__ outp){
    __shared__ float sd[512];
    int b = blockIdx.x; int gid = b >> 2, chunk = b & 3;
    int tid = threadIdx.x; int c = tid & 63, rs = tid >> 6;
    int s = gstart[gid], e = gstart[gid + 1];
    float2 rv = ((const float2*)qR0)[c];
    float a0 = 0.f, a1 = 0.f;
    for (int n = s + chunk * 4 + rs; n < e; n += 16){
        float2 v = x2[n * 64 + c];
        int i0 = (int)rintf(v.x * rv.x) + 128; i0 = min(max(i0, 0), 255);
        int i1 = (int)rintf(v.y * rv.y) + 128; i1 = min(max(i1, 0), 255);
        h8u[n * 64 + c] = (unsigned short)(i0 | (i1 << 8));
        a0 += v.x; a1 += v.y;
    }
    sd[tid] = a0; sd[256 + tid] = a1; __syncthreads();
    if (tid < 64){
        float r0 = 0.f, r1 = 0.f;
        #pragma unroll
        for (int k2 = 0; k2 < 4; k2++){ r0 += sd[tid + 64 * k2]; r1 += sd[256 + tid + 64 * k2]; }
        atomicAdd(&outp[gid * 128 + 2 * tid], r0);
        atomicAdd(&outp[gid * 128 + 2 * tid + 1], r1);
    }
}

// ---------------- per-layer kernels ----------------

// z = Dc * (selfcode + sum of neighbor codes - off*(deg+1)).
// ushort payload: 64 lanes x 2 B = 128 B = one cache line per edge, wave-uniform
// row base (scalar-pipe indices), 16 loads in flight. Exact integer accumulate.
__global__ __launch_bounds__(256) void agg_k(const unsigned short* __restrict__ h8u,
                                             const int* __restrict__ rp,
                                             const int* __restrict__ ssort,
                                             const float* __restrict__ qD,
                                             float offv,
                                             unsigned* __restrict__ z32,
                                             float* __restrict__ zstats){
    int tid = threadIdx.x;
    if (blockIdx.x == 0) zstats[tid] = 0.f;
    int n = blockIdx.x * 4 + (tid >> 6);  // grid*4 == NN exactly
    int lane = tid & 63;
    int e  = __builtin_amdgcn_readfirstlane(rp[n]);
    int e1 = __builtin_amdgcn_readfirstlane(rp[n + 1]);
    int deg = e1 - e;
    unsigned su = (unsigned)h8u[n * 64 + lane];      // self code (same scale)
    unsigned acc0 = su & 0xFFu, acc1 = su >> 8;
    for (; e + 15 < e1; e += 16){
        int sA[16];
        #pragma unroll
        for (int k = 0; k < 16; k++) sA[k] = ssort[e + k];       // uniform -> scalar
        unsigned uA[16];
        #pragma unroll
        for (int k = 0; k < 16; k++) uA[k] = (unsigned)h8u[sA[k] * 64 + lane];
        #pragma unroll
        for (int k = 0; k < 16; k++){ acc0 += uA[k] & 0xFFu; acc1 += uA[k] >> 8; }
    }
    for (; e + 3 < e1; e += 4){
        int s0 = ssort[e], s1 = ssort[e + 1], s2 = ssort[e + 2], s3 = ssort[e + 3];
        unsigned u0 = (unsigned)h8u[s0 * 64 + lane];
        unsigned u1 = (unsigned)h8u[s1 * 64 + lane];
        unsigned u2 = (unsigned)h8u[s2 * 64 + lane];
        unsigned u3 = (unsigned)h8u[s3 * 64 + lane];
        acc0 += (u0 & 0xFFu) + (u1 & 0xFFu) + (u2 & 0xFFu) + (u3 & 0xFFu);
        acc1 += (u0 >> 8) + (u1 >> 8) + (u2 >> 8) + (u3 >> 8);
    }
    for (; e < e1; ++e){
        unsigned u0 = (unsigned)h8u[ssort[e] * 64 + lane];
        acc0 += u0 & 0xFFu; acc1 += u0 >> 8;
    }
    float2 qd = ((const float2*)qD)[lane];
    float degoff = offv * (float)(deg + 1);          // self included
    float z0 = qd.x * ((float)acc0 - degoff);
    float z1 = qd.y * ((float)acc1 - degoff);
    z32[n * 64 + lane] = packbf(z0, z1);
}

// C[N, 64-col slice] = opt_relu_bn(A[N,128]) @ W-slice + bias, bf16 MFMA 16x16x32.
// v2: 64-row x 64-col tiles -> grid 1564 (6.1 blocks/CU): doubles resident waves
// to hide A-load latency. One row-frag per wave (16 rows), acc[4].
// TR==1 tracks column max/min of the output (pre-bf16) -> mst for int8 scales.
template<int TR>
__global__ __launch_bounds__(256) void gemm_k(const unsigned* __restrict__ A32,
                                              const unsigned short* __restrict__ Wtg,
                                              const float* __restrict__ bias,
                                              unsigned short* __restrict__ Cst,
                                              const float* __restrict__ stats,
                                              const float* __restrict__ gma,
                                              const float* __restrict__ bta,
                                              float* __restrict__ ostats,
                                              float* __restrict__ zstats,
                                              float* __restrict__ zpool,
                                              unsigned* __restrict__ mst){
    __shared__ __align__(16) unsigned short Wl[64 * WPAD];  // 17.4KB, [j][k] padded
    __shared__ float sred[1024];
    __shared__ __align__(16) float sl[128], tl[128];
    int tid = threadIdx.x;
    int slice = blockIdx.x & 1;
    int tileb = blockIdx.x >> 1;

    // ---- issue A-loads first: latency overlaps W-staging + barrier ----
    int wv = tid >> 6, lane = tid & 63;
    int rowbase = tileb * 64 + wv * 16;
    int r0 = rowbase + (lane & 15);
    int kd = (lane >> 4) * 4;       // dword offset within 16-dword k-group
    uint4 va[4];
    #pragma unroll
    for (int ks = 0; ks < 4; ks++)
        va[ks] = (r0 < NN) ? *(const uint4*)(A32 + r0 * 64 + ks * 16 + kd) : make_uint4(0,0,0,0);

    if (blockIdx.x == 0 && zstats) zstats[tid] = 0.f;
    if (zpool && blockIdx.x < 256) zpool[blockIdx.x * 256 + tid] = 0.f;
    {   // stage 64 W^T rows [slice*64, slice*64+64): each row = 16 uint4, padded to 17
        const uint4* src = (const uint4*)(Wtg + slice * 64 * 128);
        uint4* dst = (uint4*)Wl;
        #pragma unroll
        for (int i = 0; i < 4; i++){
            int idx = tid + 256 * i;            // 0..1023
            int row = idx >> 4, c16 = idx & 15; // 64 rows x 16 uint4
            dst[row * (WPAD / 8) + c16] = src[idx];
        }
    }
    if (TR && tid < 128){
        float mean = stats[tid] * INV_N;
        float q    = stats[128 + tid] * INV_N;
        float inv  = rsqrtf(q - mean * mean + BN_EPS);
        float s    = gma[tid] * inv;
        sl[tid] = s; tl[tid] = bta[tid] - mean * s;
    }
    __syncthreads();

    if (TR){
        #pragma unroll
        for (int ks = 0; ks < 4; ks++){
            int q = ks * 8 + (lane >> 4) * 2;       // float4 index: k0/4
            float4 sA = ((const float4*)sl)[q], sB = ((const float4*)sl)[q + 1];
            float4 tA = ((const float4*)tl)[q], tB = ((const float4*)tl)[q + 1];
            float fs[8] = {sA.x, sA.y, sA.z, sA.w, sB.x, sB.y, sB.z, sB.w};
            float ft[8] = {tA.x, tA.y, tA.z, tA.w, tB.x, tB.y, tB.z, tB.w};
            unsigned* pa = (unsigned*)&va[ks];
            #pragma unroll
            for (int c = 0; c < 4; c++){
                float f0 = fmaxf(bflo(pa[c]) * fs[2*c] + ft[2*c], 0.f);
                float f1 = fmaxf(bfhi(pa[c]) * fs[2*c+1] + ft[2*c+1], 0.f);
                pa[c] = packbf(f0, f1);
            }
        }
    }

    f32x4 acc[4];
    #pragma unroll
    for (int ct = 0; ct < 4; ct++) acc[ct] = (f32x4){0.f, 0.f, 0.f, 0.f};

    #pragma unroll
    for (int ks = 0; ks < 4; ks++){
        int wk = ks * 32 + (lane >> 4) * 8;
        bf16x8 a0 = asfrag(va[ks]);
        #pragma unroll
        for (int ct = 0; ct < 4; ++ct){
            bf16x8 b = ldfrag(&Wl[(ct * 16 + (lane & 15)) * WPAD + wk]);
            acc[ct] = __builtin_amdgcn_mfma_f32_16x16x32_bf16(a0, b, acc[ct], 0, 0, 0);
        }
    }

    // epilogue: C/D layout col=lane&15, row=(lane>>4)*4+reg. Store + column stats.
    int cl = lane & 15, rq = lane >> 4;
    float colS[4], colQ[4];
    #pragma unroll
    for (int ct = 0; ct < 4; ++ct){
        int col = slice * 64 + ct * 16 + cl;
        float bv = bias[col];
        float ps = 0.f, pq = 0.f;
        float vx = -3.4e38f, vn = -3.4e38f;
        #pragma unroll
        for (int rr2 = 0; rr2 < 4; ++rr2){
            int grow = rowbase + rq * 4 + rr2;
            if (grow < NN){
                float val = acc[ct][rr2] + bv;
                Cst[grow * 128 + col] = f2bf(val);
                ps += val; pq += val * val;
                if (TR){ vx = fmaxf(vx, val); vn = fmaxf(vn, -val); }
            }
        }
        ps += __shfl_xor(ps, 16); pq += __shfl_xor(pq, 16);
        ps += __shfl_xor(ps, 32); pq += __shfl_xor(pq, 32);
        colS[ct] = ps; colQ[ct] = pq;
        if (TR){
            vx = fmaxf(vx, __shfl_xor(vx, 16)); vx = fmaxf(vx, __shfl_xor(vx, 32));
            vn = fmaxf(vn, __shfl_xor(vn, 16)); vn = fmaxf(vn, __shfl_xor(vn, 32));
            if (rq == 0){
                sred[512 + wv * 64 + ct * 16 + cl] = vx;
                sred[768 + wv * 64 + ct * 16 + cl] = vn;
            }
        }
    }
    if (rq == 0){
        #pragma unroll
        for (int ct = 0; ct < 4; ++ct){
            sred[wv * 64 + ct * 16 + cl]       = colS[ct];
            sred[256 + wv * 64 + ct * 16 + cl] = colQ[ct];
        }
    }
    __syncthreads();
    if (tid < 64){
        float s1 = sred[tid] + sred[64 + tid] + sred[128 + tid] + sred[192 + tid];
        float s2 = sred[256 + tid] + sred[320 + tid] + sred[384 + tid] + sred[448 + tid];
        atomicAdd(&ostats[slice * 64 + tid], s1);
        atomicAdd(&ostats[128 + slice * 64 + tid], s2);
        if (TR){
            float mx = fmaxf(fmaxf(sred[512 + tid], sred[576 + tid]),
                             fmaxf(sred[640 + tid], sred[704 + tid]));
            float mn = fmaxf(fmaxf(sred[768 + tid], sred[832 + tid]),
                             fmaxf(sred[896 + tid], sred[960 + tid]));
            atomicMax(&mst[slice * 64 + tid], encf(mx));
            atomicMax(&mst[128 + slice * 64 + tid], encf(mn));
        }
    }
}

// h = relu(bn(z)) -> int8 codes only, fused with pooling.
// int8 scale derived exactly from z2 col max/min (mst) through the monotone bn map;
// block 0 publishes next-layer decode steps qDn.
__global__ __launch_bounds__(256) void ewpool_k(const unsigned* __restrict__ z32,
                                                const float* __restrict__ stats,
                                                const float* __restrict__ g,
                                                const float* __restrict__ b,
                                                const int* __restrict__ gstart,
                                                unsigned short* __restrict__ h8u,
                                                const unsigned* __restrict__ mst,
                                                float* __restrict__ qDn,
                                                float* __restrict__ outp){
    __shared__ float sd[512];
    int blk = blockIdx.x; int gid = blk >> 2, chunk = blk & 3;
    int tid = threadIdx.x;
    int c = tid & 63, rs = tid >> 6;
    int c2 = c * 2;
    float m0 = stats[c2] * INV_N,     q0 = stats[128 + c2] * INV_N;
    float inv0 = rsqrtf(q0 - m0 * m0 + BN_EPS);
    float s0 = g[c2] * inv0, t0 = b[c2] - m0 * s0;
    float m1 = stats[c2 + 1] * INV_N, q1 = stats[129 + c2] * INV_N;
    float inv1 = rsqrtf(q1 - m1 * m1 + BN_EPS);
    float s1 = g[c2 + 1] * inv1, t1 = b[c2 + 1] - m1 * s1;
    // exact column hmax through monotone affine bn + relu
    float zx0 = decf(mst[c2]),      zn0 = -decf(mst[128 + c2]);
    float zx1 = decf(mst[c2 + 1]),  zn1 = -decf(mst[129 + c2]);
    float hm0 = fmaxf(fmaxf(s0 * zx0 + t0, s0 * zn0 + t0), 0.f);
    float hm1 = fmaxf(fmaxf(s1 * zx1 + t1, s1 * zn1 + t1), 0.f);
    float r80 = (hm0 > 0.f) ? 255.f / hm0 : 0.f;
    float r81 = (hm1 > 0.f) ? 255.f / hm1 : 0.f;
    if (blk == 0 && rs == 0){
        qDn[c2]     = hm0 * (1.f / 255.f);
        qDn[c2 + 1] = hm1 * (1.f / 255.f);
    }
    int s = gstart[gid], e = gstart[gid + 1];
    float a0 = 0.f, a1 = 0.f;
    int n = s + chunk * 4 + rs;
    for (; n + 16 < e; n += 32){
        unsigned u0 = z32[n * 64 + c];
        unsigned u1 = z32[(n + 16) * 64 + c];
        float f0 = fmaxf(bflo(u0) * s0 + t0, 0.f);
        float f1 = fmaxf(bfhi(u0) * s1 + t1, 0.f);
        unsigned cu0 = (unsigned)(f0 * r80 + 0.5f); if (cu0 > 255u) cu0 = 255u;
        unsigned cu1 = (unsigned)(f1 * r81 + 0.5f); if (cu1 > 255u) cu1 = 255u;
        h8u[n * 64 + c] = (unsigned short)(cu0 | (cu1 << 8));
        a0 += f0; a1 += f1;
        f0 = fmaxf(bflo(u1) * s0 + t0, 0.f);
        f1 = fmaxf(bfhi(u1) * s1 + t1, 0.f);
        cu0 = (unsigned)(f0 * r80 + 0.5f); if (cu0 > 255u) cu0 = 255u;
        cu1 = (unsigned)(f1 * r81 + 0.5f); if (cu1 > 255u) cu1 = 255u;
        h8u[(n + 16) * 64 + c] = (unsigned short)(cu0 | (cu1 << 8));
        a0 += f0; a1 += f1;
    }
    for (; n < e; n += 16){
        unsigned u = z32[n * 64 + c];
        float f0 = fmaxf(bflo(u) * s0 + t0, 0.f);
        float f1 = fmaxf(bfhi(u) * s1 + t1, 0.f);
        unsigned cu0 = (unsigned)(f0 * r80 + 0.5f); if (cu0 > 255u) cu0 = 255u;
        unsigned cu1 = (unsigned)(f1 * r81 + 0.5f); if (cu1 > 255u) cu1 = 255u;
        h8u[n * 64 + c] = (unsigned short)(cu0 | (cu1 << 8));
        a0 += f0; a1 += f1;
    }
    sd[tid] = a0; sd[256 + tid] = a1; __syncthreads();
    if (tid < 64){
        float r0 = 0.f, r1 = 0.f;
        #pragma unroll
        for (int k2 = 0; k2 < 4; k2++){ r0 += sd[tid + 64 * k2]; r1 += sd[256 + tid + 64 * k2]; }
        atomicAdd(&outp[gid * 128 + 2 * tid], r0);
        atomicAdd(&outp[gid * 128 + 2 * tid + 1], r1);
    }
}

// logits = sum_i pooled_i @ fcW_i + fcb_i ; out = log_softmax(logits)
__global__ __launch_bounds__(64) void final_k(const float* __restrict__ pooled,
                                              const float* __restrict__ fcW,
                                              const float* __restrict__ fcb,
                                              float* __restrict__ out){
    int g = blockIdx.x, l = threadIdx.x;
    float p0[5], p1[5];
    #pragma unroll
    for (int i = 0; i < 5; i++){
        p0[i] = pooled[i * GD + g * 128 + l];
        p1[i] = pooled[i * GD + g * 128 + 64 + l];
    }
    float lg[10];
    #pragma unroll
    for (int c2 = 0; c2 < 10; c2++){
        float s = 0;
        #pragma unroll
        for (int i = 0; i < 5; i++){
            s += p0[i] * fcW[(i * 128 + l) * 10 + c2];
            s += p1[i] * fcW[(i * 128 + 64 + l) * 10 + c2];
        }
        #pragma unroll
        for (int off = 32; off >= 1; off >>= 1) s += __shfl_down(s, off);
        lg[c2] = s;
    }
    if (l == 0){
        #pragma unroll
        for (int c2 = 0; c2 < 10; c2++){
            float bs = 0;
            #pragma unroll
            for (int i = 0; i < 5; i++) bs += fcb[i * 10 + c2];
            lg[c2] += bs;
        }
        float mx = lg[0];
        #pragma unroll
        for (int c2 = 1; c2 < 10; c2++) mx = fmaxf(mx, lg[c2]);
        float se = 0;
        #pragma unroll
        for (int c2 = 0; c2 < 10; c2++) se += expf(lg[c2] - mx);
        float lse = mx + logf(se);
        #pragma unroll
        for (int c2 = 0; c2 < 10; c2++) out[g * 10 + c2] = lg[c2] - lse;
    }
}

// ---------------- launch ----------------

extern "C" void kernel_launch(void* const* d_in, const int* in_sizes, int n_in,
                              void* d_out, int out_size, void* d_ws, size_t ws_size,
                              hipStream_t stream){
    (void)in_sizes; (void)n_in; (void)out_size; (void)ws_size;
    const float* x     = (const float*)d_in[0];
    const int*   ei    = (const int*)d_in[1];
    const int*   batch = (const int*)d_in[2];
    const float* cW1   = (const float*)d_in[4];
    const float* cb1   = (const float*)d_in[5];
    const float* cbng  = (const float*)d_in[6];
    const float* cbnb  = (const float*)d_in[7];
    const float* cW2   = (const float*)d_in[8];
    const float* cb2   = (const float*)d_in[9];
    const float* bng   = (const float*)d_in[10];
    const float* bnb   = (const float*)d_in[11];
    const float* fcW   = (const float*)d_in[12];
    const float* fcb   = (const float*)d_in[13];

    char* base = (char*)d_ws;
    size_t off = 0;
    auto alloc = [&](size_t bytes) -> void* {
        void* p = base + off;
        off = (off + bytes + 255) & ~(size_t)255;
        return p;
    };
    unsigned*       zA     = (unsigned*)alloc((size_t)NN * 64 * 4);
    unsigned*       zB     = (unsigned*)alloc((size_t)NN * 64 * 4);   // also binned (NB*BUCKCAP*4 = 12.54MB)
    unsigned short* h8     = (unsigned short*)alloc((size_t)NN * 64 * 2);  // int8 codes of h
    unsigned short* Wtall  = (unsigned short*)alloc(8 * 16384 * 2);
    int*            ssort  = (int*)alloc((size_t)EE * 4);
    int*            rp     = (int*)alloc((NN + 1) * 4);
    int*            gstart = (int*)alloc((GG + 1) * 4);
    int*            bucketBase = (int*)alloc((NB + 1) * 4);
    // ---- contiguous zero region: bucketCur .. pooled slot 0 ----
    int*            bucketCur  = (int*)alloc(NB * 4);
    unsigned*       xmaxE  = (unsigned*)alloc(128 * 4);
    unsigned*       mstats = (unsigned*)alloc((size_t)LLAY * 256 * 4);
    float*          pooled = (float*)alloc((size_t)5 * GD * 4);
    // ------------------------------------------------------------
    float*          stats1 = (float*)alloc(256 * 4);
    float*          stats2 = (float*)alloc(256 * 4);
    float*          qD     = (float*)alloc(5 * 128 * 4);   // per-layer decode steps
    float*          qR     = (float*)alloc(128 * 4);       // layer-0 encode scale
    unsigned*       binned = (unsigned*)zB;   // alias: binned only used before layer loop

    int zwords = (int)(((char*)(pooled + GD) - (char*)bucketCur) / 4);  // incl. pooled[0] slot

    zero_k<<<(zwords + 255) / 256, 256, 0, stream>>>(bucketCur, zwords);
    wprep_k<<<512, 256, 0, stream>>>(cW1, cW2, Wtall);
    gsearch_k<<<3, 256, 0, stream>>>(batch, gstart);
    binA_k<<<(EE + BK_EDGES - 1) / BK_EDGES, 256, 0, stream>>>(ei, ei + EE, bucketCur, binned);
    bscan_k<<<1, 256, 0, stream>>>(bucketCur, bucketBase, rp);
    binB_k<<<NB, 1024, 0, stream>>>(binned, bucketCur, bucketBase, rp, ssort);
    xmax_k<<<512, 256, 0, stream>>>(x, xmaxE);
    qx_k<<<1, 128, 0, stream>>>(xmaxE, qD, qR);
    convxpool_k<<<4 * GG, 256, 0, stream>>>((const float2*)x, gstart, h8, qR, pooled);

    const int gemmGrid = 2 * ((NN + 63) / 64);   // 1564 blocks (64-row tiles)
    for (int i = 0; i < LLAY; i++){
        agg_k<<<NN / 4, 256, 0, stream>>>(h8, rp, ssort,
                                          qD + i * 128, (i == 0) ? 128.f : 0.f, zA, stats1);
        gemm_k<0><<<gemmGrid, 256, 0, stream>>>(zA, Wtall + i * 16384, cb1 + i * 128,
                                                (unsigned short*)zB,
                                                nullptr, nullptr, nullptr, stats1, stats2,
                                                nullptr, nullptr);
        gemm_k<1><<<gemmGrid, 256, 0, stream>>>(zB, Wtall + (4 + i) * 16384, cb2 + i * 128,
                                                (unsigned short*)zA,
                                                stats1, cbng + i * 128, cbnb + i * 128, stats2,
                                                nullptr, pooled + (size_t)(i + 1) * GD,
                                                mstats + (size_t)i * 256);
        ewpool_k<<<4 * GG, 256, 0, stream>>>(zA, stats2, bng + i * 128, bnb + i * 128,
                                             gstart, h8, mstats + (size_t)i * 256,
                                             qD + (i + 1) * 128,
                                             pooled + (size_t)(i + 1) * GD);
    }
    final_k<<<GG, 64, 0, stream>>>(pooled, fcW, fcb, (float*)d_out);
}

// Round 11
// 507.715 us; speedup vs baseline: 1.1914x; 1.1914x over previous
//
#include <hip/hip_runtime.h>

#define NN 50000
#define EE 1600000
#define DD 128
#define CC 10
#define LLAY 4
#define GG 512
#define GD (GG*DD)
#define NB 196           // ceil(NN/256) coarse buckets
#define BK_EDGES 1024    // edges per binA block (1563 blocks)
#define BUCKCAP 16000    // fixed binned region per bucket (expected 8192, >8 sigma safe)
#define NSUB 16          // src sub-tiles per node list (sorted gather window)
#define SUBW 3125        // 50000/16
#define WPAD 136         // Wl row stride in shorts (272B = 17 uint4: 2-way banks = free)
#define NSLOT 8          // replicated stat slots (atomic contention / 8)

static constexpr float BN_EPS = 1e-5f;
static constexpr float INV_N = 1.0f / (float)NN;

typedef __bf16 bf16x8 __attribute__((ext_vector_type(8)));
typedef float f32x4 __attribute__((ext_vector_type(4)));

static __device__ __forceinline__ float bflo(unsigned u){ return __uint_as_float(u << 16); }
static __device__ __forceinline__ float bfhi(unsigned u){ return __uint_as_float(u & 0xffff0000u); }
static __device__ __forceinline__ unsigned short f2bf(float f){
    unsigned u = __float_as_uint(f);
    return (unsigned short)((u + 0x7fffu + ((u >> 16) & 1u)) >> 16);   // RNE
}
static __device__ __forceinline__ unsigned packbf(float a, float b){
    return (unsigned)f2bf(a) | ((unsigned)f2bf(b) << 16);
}
// order-preserving float<->uint for atomicMax on signed floats (0 = identity)
static __device__ __forceinline__ unsigned encf(float f){
    unsigned b = __float_as_uint(f);
    return (b & 0x80000000u) ? ~b : (b | 0x80000000u);
}
static __device__ __forceinline__ float decf(unsigned e){
    unsigned b = (e & 0x80000000u) ? (e ^ 0x80000000u) : ~e;
    return __uint_as_float(b);
}
static __device__ __forceinline__ bf16x8 ldfrag(const unsigned short* p){
    union { uint4 u; bf16x8 b; } t; t.u = *(const uint4*)p; return t.b;
}
static __device__ __forceinline__ bf16x8 asfrag(uint4 u){
    union { uint4 u; bf16x8 b; } t; t.u = u; return t.b;
}

// ---------------- setup kernels ----------------

__global__ void zero_k(int* p, int n){
    int i = blockIdx.x * 256 + threadIdx.x;
    if (i < n) p[i] = 0;
}

// all 8 weight matrices -> bf16 W^T [j][k] in ws
__global__ void wprep_k(const float* __restrict__ W1, const float* __restrict__ W2,
                        unsigned short* __restrict__ Wtall){
    int idx = blockIdx.x * 256 + threadIdx.x;         // < 8*16384
    int mat = idx >> 14; int rr = idx & 16383;
    int k = rr >> 7; int j = rr & 127;
    const float* Wsrc = (mat < 4) ? (W1 + mat * 16384) : (W2 + (mat - 4) * 16384);
    Wtall[mat * 16384 + j * 128 + k] = f2bf(Wsrc[k * 128 + j]);
}

// graph boundaries via binary search on sorted batch
__global__ void gsearch_k(const int* __restrict__ batch, int* __restrict__ gstart){
    int g = blockIdx.x * 256 + threadIdx.x;
    if (g <= GG){
        int lo = 0, hi = NN;
        while (lo < hi){ int mid = (lo + hi) >> 1; if (batch[mid] < g) lo = mid + 1; else hi = mid; }
        gstart[g] = lo;
    }
}

// Pass A: bin edges into NB bucket regions with COALESCED writes (counting sort).
__global__ __launch_bounds__(256) void binA_k(const int* __restrict__ srcA,
                                              const int* __restrict__ dstA,
                                              int* __restrict__ bucketCur,
                                              unsigned* __restrict__ binned){
    __shared__ int cnt[256];           // per-bucket counts (NB <= 256)
    __shared__ int lb[256];            // scan buffer -> local exclusive base
    __shared__ int bas[NB];            // global base per bucket
    __shared__ int off[NB];            // running offset for LDS scatter
    __shared__ unsigned stage[BK_EDGES];
    __shared__ int tots;
    int tid = threadIdx.x;
    cnt[tid] = 0;
    if (tid < NB) off[tid] = 0;
    __syncthreads();
    int e0 = blockIdx.x * BK_EDGES;
    int myB[4]; unsigned myVal[4];
    #pragma unroll
    for (int k = 0; k < 4; k++){
        int e = e0 + tid + k * 256;
        bool v = (e < EE);
        int d = v ? dstA[e] : -1;
        int s = v ? srcA[e] : 0;
        myB[k] = v ? (d >> 8) : -1;
        myVal[k] = (unsigned)s | ((unsigned)(d & 255) << 17);   // src<2^17
        if (v) atomicAdd(&cnt[d >> 8], 1);
    }
    __syncthreads();
    int v = cnt[tid];
    lb[tid] = v; __syncthreads();
    for (int o = 1; o < 256; o <<= 1){                 // Hillis-Steele inclusive scan
        int x = 0; if (tid >= o) x = lb[tid - o];
        __syncthreads(); lb[tid] += x; __syncthreads();
    }
    int incl = lb[tid];
    if (tid == 255) tots = incl;
    __syncthreads();
    lb[tid] = incl - v;                                // exclusive base
    if (tid < NB && v > 0) bas[tid] = atomicAdd(&bucketCur[tid], v);
    __syncthreads();
    #pragma unroll
    for (int k = 0; k < 4; k++){
        int b = myB[k];
        if (b >= 0){
            int p = lb[b] + atomicAdd(&off[b], 1);
            stage[p] = myVal[k];
        }
    }
    __syncthreads();
    int tot = tots;
    for (int i = tid; i < tot; i += 256){
        int lo = 0, hi = NB - 1;                       // largest b with lb[b] <= i
        while (lo < hi){
            int mid = (lo + hi + 1) >> 1;
            if (lb[mid] <= i) lo = mid; else hi = mid - 1;
        }
        binned[lo * BUCKCAP + bas[lo] + (i - lb[lo])] = stage[i];
    }
}

// scan bucket counts (post-binA) -> bucketBase; terminal rp entry
__global__ __launch_bounds__(256) void bscan_k(const int* __restrict__ bucketCur,
                                               int* __restrict__ bucketBase,
                                               int* __restrict__ rp){
    __shared__ int lds[256];
    int t = threadIdx.x;
    int v = (t < NB) ? bucketCur[t] : 0;
    lds[t] = v; __syncthreads();
    for (int o = 1; o < 256; o <<= 1){
        int xv = 0; if (t >= o) xv = lds[t - o];
        __syncthreads(); lds[t] += xv; __syncthreads();
    }
    int excl = lds[t] - v;
    if (t < NB) bucketBase[t] = excl;
    if (t == 0){ bucketBase[NB] = EE; rp[NN] = EE; }
}

// Pass B (1024 thr): per-bucket (node, 16-subtile) counts -> rp + src-sorted placement.
__global__ __launch_bounds__(1024) void binB_k(const unsigned* __restrict__ binned,
                                               const int* __restrict__ bucketCur,
                                               const int* __restrict__ bucketBase,
                                               int* __restrict__ rp,
                                               int* __restrict__ ssort){
    __shared__ int c16[256 * NSUB];   // 16 KB
    __shared__ int b16[256 * NSUB];   // 16 KB
    __shared__ int nt[256];
    int b = blockIdx.x, tid = threadIdx.x;
    int nb0 = b * 256;
    int nmax = NN - nb0; if (nmax > 256) nmax = 256;
    for (int i = tid; i < 256 * NSUB; i += 1024) c16[i] = 0;
    __syncthreads();
    int cntb = bucketCur[b];
    int src0 = b * BUCKCAP;
    int base = bucketBase[b];
    for (int i = tid; i < cntb; i += 1024){
        unsigned u = binned[src0 + i];
        int src = (int)(u & 0x1FFFFu); int dl = (int)(u >> 17);
        atomicAdd(&c16[dl * NSUB + src / SUBW], 1);
    }
    __syncthreads();
    int cc[NSUB]; int tot = 0;
    if (tid < 256){
        #pragma unroll
        for (int k = 0; k < NSUB; k++){ cc[k] = c16[tid * NSUB + k]; tot += cc[k]; }
        nt[tid] = tot;
    }
    __syncthreads();
    for (int o = 1; o < 256; o <<= 1){
        int xv = 0;
        if (tid < 256 && tid >= o) xv = nt[tid - o];
        __syncthreads();
        if (tid < 256) nt[tid] += xv;
        __syncthreads();
    }
    if (tid < 256){
        int p = base + nt[tid] - tot;
        if (tid < nmax) rp[nb0 + tid] = p;
        int run = p;
        #pragma unroll
        for (int k = 0; k < NSUB; k++){ b16[tid * NSUB + k] = run; run += cc[k]; }
    }
    __syncthreads();
    for (int i = tid; i < 256 * NSUB; i += 1024) c16[i] = 0;
    __syncthreads();
    for (int i = tid; i < cntb; i += 1024){
        unsigned u = binned[src0 + i];
        int src = (int)(u & 0x1FFFFu); int dl = (int)(u >> 17);
        int t = src / SUBW;
        int pos = b16[dl * NSUB + t] + atomicAdd(&c16[dl * NSUB + t], 1);
        ssort[pos] = src;
    }
}

// column absmax of x (for layer-0 int8 scales). nonneg floats: raw-bit atomicMax ok.
__global__ __launch_bounds__(256) void xmax_k(const float* __restrict__ x,
                                              unsigned* __restrict__ xmaxE){
    __shared__ float sm[256];
    int tid = threadIdx.x;
    int col = tid & 127, rh = tid >> 7;
    float m = 0.f;
    for (int r = blockIdx.x * 2 + rh; r < NN; r += 1024)
        m = fmaxf(m, fabsf(x[r * 128 + col]));
    sm[tid] = m; __syncthreads();
    if (tid < 128){
        m = fmaxf(sm[tid], sm[tid + 128]);
        atomicMax(&xmaxE[col], __float_as_uint(m));
    }
}

// layer-0 scales: qD[c] = xmax/127 (decode step), qR[c] = 127/xmax (encode)
__global__ void qx_k(const unsigned* __restrict__ xmaxE,
                     float* __restrict__ qD, float* __restrict__ qR){
    int c = threadIdx.x;   // 128 threads
    float m = __uint_as_float(xmaxE[c]);
    qD[c] = m * (1.f / 127.f);
    qR[c] = (m > 0.f) ? 127.f / m : 0.f;
}

// x (fp32) -> int8 codes (offset-128) only, fused with x-pooling.
__global__ __launch_bounds__(256) void convxpool_k(const float2* __restrict__ x2,
                                                   const int* __restrict__ gstart,
                                                   unsigned short* __restrict__ h8u,
                                                   const float* __restrict__ qR0,
                                                   float* __restrict__ outp){
    __shared__ float sd[512];
    int b = blockIdx.x; int gid = b >> 2, chunk = b & 3;
    int tid = threadIdx.x; int c = tid & 63, rs = tid >> 6;
    int s = gstart[gid], e = gstart[gid + 1];
    float2 rv = ((const float2*)qR0)[c];
    float a0 = 0.f, a1 = 0.f;
    for (int n = s + chunk * 4 + rs; n < e; n += 16){
        float2 v = x2[n * 64 + c];
        int i0 = (int)rintf(v.x * rv.x) + 128; i0 = min(max(i0, 0), 255);
        int i1 = (int)rintf(v.y * rv.y) + 128; i1 = min(max(i1, 0), 255);
        h8u[n * 64 + c] = (unsigned short)(i0 | (i1 << 8));
        a0 += v.x; a1 += v.y;
    }
    sd[tid] = a0; sd[256 + tid] = a1; __syncthreads();
    if (tid < 64){
        float r0 = 0.f, r1 = 0.f;
        #pragma unroll
        for (int k2 = 0; k2 < 4; k2++){ r0 += sd[tid + 64 * k2]; r1 += sd[256 + tid + 64 * k2]; }
        atomicAdd(&outp[gid * 128 + 2 * tid], r0);
        atomicAdd(&outp[gid * 128 + 2 * tid + 1], r1);
    }
}

// ---------------- per-layer kernels ----------------

// z = Dc * (selfcode + sum of neighbor codes - off*(deg+1)).
// ushort payload: 64 lanes x 2 B = 128 B = one cache line per edge, wave-uniform
// row base (scalar-pipe indices), 16 loads in flight. Exact integer accumulate.
__global__ __launch_bounds__(256) void agg_k(const unsigned short* __restrict__ h8u,
                                             const int* __restrict__ rp,
                                             const int* __restrict__ ssort,
                                             const float* __restrict__ qD,
                                             float offv,
                                             unsigned* __restrict__ z32){
    int tid = threadIdx.x;
    int n = blockIdx.x * 4 + (tid >> 6);  // grid*4 == NN exactly
    int lane = tid & 63;
    int e  = __builtin_amdgcn_readfirstlane(rp[n]);
    int e1 = __builtin_amdgcn_readfirstlane(rp[n + 1]);
    int deg = e1 - e;
    unsigned su = (unsigned)h8u[n * 64 + lane];      // self code (same scale)
    unsigned acc0 = su & 0xFFu, acc1 = su >> 8;
    for (; e + 15 < e1; e += 16){
        int sA[16];
        #pragma unroll
        for (int k = 0; k < 16; k++) sA[k] = ssort[e + k];       // uniform -> scalar
        unsigned uA[16];
        #pragma unroll
        for (int k = 0; k < 16; k++) uA[k] = (unsigned)h8u[sA[k] * 64 + lane];
        #pragma unroll
        for (int k = 0; k < 16; k++){ acc0 += uA[k] & 0xFFu; acc1 += uA[k] >> 8; }
    }
    for (; e + 3 < e1; e += 4){
        int s0 = ssort[e], s1 = ssort[e + 1], s2 = ssort[e + 2], s3 = ssort[e + 3];
        unsigned u0 = (unsigned)h8u[s0 * 64 + lane];
        unsigned u1 = (unsigned)h8u[s1 * 64 + lane];
        unsigned u2 = (unsigned)h8u[s2 * 64 + lane];
        unsigned u3 = (unsigned)h8u[s3 * 64 + lane];
        acc0 += (u0 & 0xFFu) + (u1 & 0xFFu) + (u2 & 0xFFu) + (u3 & 0xFFu);
        acc1 += (u0 >> 8) + (u1 >> 8) + (u2 >> 8) + (u3 >> 8);
    }
    for (; e < e1; ++e){
        unsigned u0 = (unsigned)h8u[ssort[e] * 64 + lane];
        acc0 += u0 & 0xFFu; acc1 += u0 >> 8;
    }
    float2 qd = ((const float2*)qD)[lane];
    float degoff = offv * (float)(deg + 1);          // self included
    float z0 = qd.x * ((float)acc0 - degoff);
    float z1 = qd.y * ((float)acc1 - degoff);
    z32[n * 64 + lane] = packbf(z0, z1);
}

// C[N, 64-col slice] = opt_relu_bn(A[N,128]) @ W-slice + bias, bf16 MFMA 16x16x32.
// 128-row x 64-col tile (782 blocks, the long-verified shape). Stats go to one of
// NSLOT replicated 256-word slots (slot = (blockIdx>>1)&7) -> atomic contention /8.
// TR==1: consumes 8-slot stats (sum) and tracks col max/min into 8-slot mst.
template<int TR>
__global__ __launch_bounds__(256) void gemm_k(const unsigned* __restrict__ A32,
                                              const unsigned short* __restrict__ Wtg,
                                              const float* __restrict__ bias,
                                              unsigned short* __restrict__ Cst,
                                              const float* __restrict__ stats,
                                              const float* __restrict__ gma,
                                              const float* __restrict__ bta,
                                              float* __restrict__ ostats,
                                              float* __restrict__ zpool,
                                              unsigned* __restrict__ mst){
    __shared__ __align__(16) unsigned short Wl[64 * WPAD];  // 17.4KB, [j][k] padded
    __shared__ float sred[1024];
    __shared__ __align__(16) float sl[128], tl[128];
    int tid = threadIdx.x;
    int slice = blockIdx.x & 1;
    int tileb = blockIdx.x >> 1;
    int slot = tileb & (NSLOT - 1);

    // ---- issue A-loads first: their ~L3 latency overlaps W-staging + barrier ----
    int wv = tid >> 6, lane = tid & 63;
    int rowbase = tileb * 128 + wv * 32;
    int r0 = rowbase + (lane & 15);
    int r1 = r0 + 16;
    int kd = (lane >> 4) * 4;       // dword offset within 16-dword k-group
    uint4 va[4], vb[4];
    #pragma unroll
    for (int ks = 0; ks < 4; ks++){
        va[ks] = (r0 < NN) ? *(const uint4*)(A32 + r0 * 64 + ks * 16 + kd) : make_uint4(0,0,0,0);
        vb[ks] = (r1 < NN) ? *(const uint4*)(A32 + r1 * 64 + ks * 16 + kd) : make_uint4(0,0,0,0);
    }

    if (zpool && blockIdx.x < 256) zpool[blockIdx.x * 256 + tid] = 0.f;
    {   // stage 64 W^T rows [slice*64, slice*64+64): each row = 16 uint4, padded to 17
        const uint4* src = (const uint4*)(Wtg + slice * 64 * 128);
        uint4* dst = (uint4*)Wl;
        #pragma unroll
        for (int i = 0; i < 4; i++){
            int idx = tid + 256 * i;            // 0..1023
            int row = idx >> 4, c16 = idx & 15; // 64 rows x 16 uint4
            dst[row * (WPAD / 8) + c16] = src[idx];
        }
    }
    if (TR && tid < 128){
        float sum1 = 0.f, sum2 = 0.f;
        #pragma unroll
        for (int s8 = 0; s8 < NSLOT; s8++){
            sum1 += stats[s8 * 256 + tid];
            sum2 += stats[s8 * 256 + 128 + tid];
        }
        float mean = sum1 * INV_N;
        float q    = sum2 * INV_N;
        float inv  = rsqrtf(q - mean * mean + BN_EPS);
        float s    = gma[tid] * inv;
        sl[tid] = s; tl[tid] = bta[tid] - mean * s;
    }
    __syncthreads();

    if (TR){
        #pragma unroll
        for (int ks = 0; ks < 4; ks++){
            int q = ks * 8 + (lane >> 4) * 2;       // float4 index: k0/4
            float4 sA = ((const float4*)sl)[q], sB = ((const float4*)sl)[q + 1];
            float4 tA = ((const float4*)tl)[q], tB = ((const float4*)tl)[q + 1];
            float fs[8] = {sA.x, sA.y, sA.z, sA.w, sB.x, sB.y, sB.z, sB.w};
            float ft[8] = {tA.x, tA.y, tA.z, tA.w, tB.x, tB.y, tB.z, tB.w};
            unsigned* pa = (unsigned*)&va[ks];
            unsigned* pb = (unsigned*)&vb[ks];
            #pragma unroll
            for (int c = 0; c < 4; c++){
                float f0 = fmaxf(bflo(pa[c]) * fs[2*c] + ft[2*c], 0.f);
                float f1 = fmaxf(bfhi(pa[c]) * fs[2*c+1] + ft[2*c+1], 0.f);
                pa[c] = packbf(f0, f1);
                f0 = fmaxf(bflo(pb[c]) * fs[2*c] + ft[2*c], 0.f);
                f1 = fmaxf(bfhi(pb[c]) * fs[2*c+1] + ft[2*c+1], 0.f);
                pb[c] = packbf(f0, f1);
            }
        }
    }

    f32x4 acc[2][4];
    #pragma unroll
    for (int a = 0; a < 2; a++)
        #pragma unroll
        for (int b = 0; b < 4; b++) acc[a][b] = (f32x4){0.f, 0.f, 0.f, 0.f};

    #pragma unroll
    for (int ks = 0; ks < 4; ks++){
        int wk = ks * 32 + (lane >> 4) * 8;
        bf16x8 a0 = asfrag(va[ks]);
        bf16x8 a1 = asfrag(vb[ks]);
        #pragma unroll
        for (int ct = 0; ct < 4; ++ct){
            bf16x8 b = ldfrag(&Wl[(ct * 16 + (lane & 15)) * WPAD + wk]);
            acc[0][ct] = __builtin_amdgcn_mfma_f32_16x16x32_bf16(a0, b, acc[0][ct], 0, 0, 0);
            acc[1][ct] = __builtin_amdgcn_mfma_f32_16x16x32_bf16(a1, b, acc[1][ct], 0, 0, 0);
        }
    }

    // epilogue: C/D layout col=lane&15, row=(lane>>4)*4+reg. Store + column stats.
    int cl = lane & 15, rq = lane >> 4;
    float colS[4], colQ[4];
    #pragma unroll
    for (int ct = 0; ct < 4; ++ct){
        int col = slice * 64 + ct * 16 + cl;
        float bv = bias[col];
        float ps = 0.f, pq = 0.f;
        float vx = -3.4e38f, vn = -3.4e38f;
        #pragma unroll
        for (int rt = 0; rt < 2; ++rt){
            #pragma unroll
            for (int rr2 = 0; rr2 < 4; ++rr2){
                int grow = rowbase + rt * 16 + rq * 4 + rr2;
                if (grow < NN){
                    float val = acc[rt][ct][rr2] + bv;
                    Cst[grow * 128 + col] = f2bf(val);
                    ps += val; pq += val * val;
                    if (TR){ vx = fmaxf(vx, val); vn = fmaxf(vn, -val); }
                }
            }
        }
        ps += __shfl_xor(ps, 16); pq += __shfl_xor(pq, 16);
        ps += __shfl_xor(ps, 32); pq += __shfl_xor(pq, 32);
        colS[ct] = ps; colQ[ct] = pq;
        if (TR){
            vx = fmaxf(vx, __shfl_xor(vx, 16)); vx = fmaxf(vx, __shfl_xor(vx, 32));
            vn = fmaxf(vn, __shfl_xor(vn, 16)); vn = fmaxf(vn, __shfl_xor(vn, 32));
            if (rq == 0){
                sred[512 + wv * 64 + ct * 16 + cl] = vx;
                sred[768 + wv * 64 + ct * 16 + cl] = vn;
            }
        }
    }
    if (rq == 0){
        #pragma unroll
        for (int ct = 0; ct < 4; ++ct){
            sred[wv * 64 + ct * 16 + cl]       = colS[ct];
            sred[256 + wv * 64 + ct * 16 + cl] = colQ[ct];
        }
    }
    __syncthreads();
    if (tid < 64){
        float s1 = sred[tid] + sred[64 + tid] + sred[128 + tid] + sred[192 + tid];
        float s2 = sred[256 + tid] + sred[320 + tid] + sred[384 + tid] + sred[448 + tid];
        atomicAdd(&ostats[slot * 256 + slice * 64 + tid], s1);
        atomicAdd(&ostats[slot * 256 + 128 + slice * 64 + tid], s2);
        if (TR){
            float mx = fmaxf(fmaxf(sred[512 + tid], sred[576 + tid]),
                             fmaxf(sred[640 + tid], sred[704 + tid]));
            float mn = fmaxf(fmaxf(sred[768 + tid], sred[832 + tid]),
                             fmaxf(sred[896 + tid], sred[960 + tid]));
            atomicMax(&mst[slot * 256 + slice * 64 + tid], encf(mx));
            atomicMax(&mst[slot * 256 + 128 + slice * 64 + tid], encf(mn));
        }
    }
}

// h = relu(bn(z)) -> int8 codes only, fused with pooling. Consumes 8-slot stats
// (sum) and 8-slot mst (max of order-preserving encodings). Block 0 publishes qDn.
__global__ __launch_bounds__(256) void ewpool_k(const unsigned* __restrict__ z32,
                                                const float* __restrict__ stats,
                                                const float* __restrict__ g,
                                                const float* __restrict__ b,
                                                const int* __restrict__ gstart,
                                                unsigned short* __restrict__ h8u,
                                                const unsigned* __restrict__ mst,
                                                float* __restrict__ qDn,
                                                float* __restrict__ outp){
    __shared__ float sd[512];
    int blk = blockIdx.x; int gid = blk >> 2, chunk = blk & 3;
    int tid = threadIdx.x;
    int c = tid & 63, rs = tid >> 6;
    int c2 = c * 2;
    float sm0 = 0.f, sq0 = 0.f, sm1 = 0.f, sq1 = 0.f;
    unsigned ex0 = 0u, en0 = 0u, ex1 = 0u, en1 = 0u;
    #pragma unroll
    for (int s8 = 0; s8 < NSLOT; s8++){
        sm0 += stats[s8 * 256 + c2];       sq0 += stats[s8 * 256 + 128 + c2];
        sm1 += stats[s8 * 256 + c2 + 1];   sq1 += stats[s8 * 256 + 129 + c2];
        ex0 = max(ex0, mst[s8 * 256 + c2]);       en0 = max(en0, mst[s8 * 256 + 128 + c2]);
        ex1 = max(ex1, mst[s8 * 256 + c2 + 1]);   en1 = max(en1, mst[s8 * 256 + 129 + c2]);
    }
    float m0 = sm0 * INV_N, q0 = sq0 * INV_N;
    float inv0 = rsqrtf(q0 - m0 * m0 + BN_EPS);
    float s0 = g[c2] * inv0, t0 = b[c2] - m0 * s0;
    float m1 = sm1 * INV_N, q1 = sq1 * INV_N;
    float inv1 = rsqrtf(q1 - m1 * m1 + BN_EPS);
    float s1 = g[c2 + 1] * inv1, t1 = b[c2 + 1] - m1 * s1;
    // exact column hmax through monotone affine bn + relu
    float zx0 = decf(ex0), zn0 = -decf(en0);
    float zx1 = decf(ex1), zn1 = -decf(en1);
    float hm0 = fmaxf(fmaxf(s0 * zx0 + t0, s0 * zn0 + t0), 0.f);
    float hm1 = fmaxf(fmaxf(s1 * zx1 + t1, s1 * zn1 + t1), 0.f);
    float r80 = (hm0 > 0.f) ? 255.f / hm0 : 0.f;
    float r81 = (hm1 > 0.f) ? 255.f / hm1 : 0.f;
    if (blk == 0 && rs == 0){
        qDn[c2]     = hm0 * (1.f / 255.f);
        qDn[c2 + 1] = hm1 * (1.f / 255.f);
    }
    int s = gstart[gid], e = gstart[gid + 1];
    float a0 = 0.f, a1 = 0.f;
    int n = s + chunk * 4 + rs;
    for (; n + 16 < e; n += 32){
        unsigned u0 = z32[n * 64 + c];
        unsigned u1 = z32[(n + 16) * 64 + c];
        float f0 = fmaxf(bflo(u0) * s0 + t0, 0.f);
        float f1 = fmaxf(bfhi(u0) * s1 + t1, 0.f);
        unsigned cu0 = (unsigned)(f0 * r80 + 0.5f); if (cu0 > 255u) cu0 = 255u;
        unsigned cu1 = (unsigned)(f1 * r81 + 0.5f); if (cu1 > 255u) cu1 = 255u;
        h8u[n * 64 + c] = (unsigned short)(cu0 | (cu1 << 8));
        a0 += f0; a1 += f1;
        f0 = fmaxf(bflo(u1) * s0 + t0, 0.f);
        f1 = fmaxf(bfhi(u1) * s1 + t1, 0.f);
        cu0 = (unsigned)(f0 * r80 + 0.5f); if (cu0 > 255u) cu0 = 255u;
        cu1 = (unsigned)(f1 * r81 + 0.5f); if (cu1 > 255u) cu1 = 255u;
        h8u[(n + 16) * 64 + c] = (unsigned short)(cu0 | (cu1 << 8));
        a0 += f0; a1 += f1;
    }
    for (; n < e; n += 16){
        unsigned u = z32[n * 64 + c];
        float f0 = fmaxf(bflo(u) * s0 + t0, 0.f);
        float f1 = fmaxf(bfhi(u) * s1 + t1, 0.f);
        unsigned cu0 = (unsigned)(f0 * r80 + 0.5f); if (cu0 > 255u) cu0 = 255u;
        unsigned cu1 = (unsigned)(f1 * r81 + 0.5f); if (cu1 > 255u) cu1 = 255u;
        h8u[n * 64 + c] = (unsigned short)(cu0 | (cu1 << 8));
        a0 += f0; a1 += f1;
    }
    sd[tid] = a0; sd[256 + tid] = a1; __syncthreads();
    if (tid < 64){
        float r0 = 0.f, r1 = 0.f;
        #pragma unroll
        for (int k2 = 0; k2 < 4; k2++){ r0 += sd[tid + 64 * k2]; r1 += sd[256 + tid + 64 * k2]; }
        atomicAdd(&outp[gid * 128 + 2 * tid], r0);
        atomicAdd(&outp[gid * 128 + 2 * tid + 1], r1);
    }
}

// logits = sum_i pooled_i @ fcW_i + fcb_i ; out = log_softmax(logits)
__global__ __launch_bounds__(64) void final_k(const float* __restrict__ pooled,
                                              const float* __restrict__ fcW,
                                              const float* __restrict__ fcb,
                                              float* __restrict__ out){
    int g = blockIdx.x, l = threadIdx.x;
    float p0[5], p1[5];
    #pragma unroll
    for (int i = 0; i < 5; i++){
        p0[i] = pooled[i * GD + g * 128 + l];
        p1[i] = pooled[i * GD + g * 128 + 64 + l];
    }
    float lg[10];
    #pragma unroll
    for (int c2 = 0; c2 < 10; c2++){
        float s = 0;
        #pragma unroll
        for (int i = 0; i < 5; i++){
            s += p0[i] * fcW[(i * 128 + l) * 10 + c2];
            s += p1[i] * fcW[(i * 128 + 64 + l) * 10 + c2];
        }
        #pragma unroll
        for (int off = 32; off >= 1; off >>= 1) s += __shfl_down(s, off);
        lg[c2] = s;
    }
    if (l == 0){
        #pragma unroll
        for (int c2 = 0; c2 < 10; c2++){
            float bs = 0;
            #pragma unroll
            for (int i = 0; i < 5; i++) bs += fcb[i * 10 + c2];
            lg[c2] += bs;
        }
        float mx = lg[0];
        #pragma unroll
        for (int c2 = 1; c2 < 10; c2++) mx = fmaxf(mx, lg[c2]);
        float se = 0;
        #pragma unroll
        for (int c2 = 0; c2 < 10; c2++) se += expf(lg[c2] - mx);
        float lse = mx + logf(se);
        #pragma unroll
        for (int c2 = 0; c2 < 10; c2++) out[g * 10 + c2] = lg[c2] - lse;
    }
}

// ---------------- launch ----------------

extern "C" void kernel_launch(void* const* d_in, const int* in_sizes, int n_in,
                              void* d_out, int out_size, void* d_ws, size_t ws_size,
                              hipStream_t stream){
    (void)in_sizes; (void)n_in; (void)out_size; (void)ws_size;
    const float* x     = (const float*)d_in[0];
    const int*   ei    = (const int*)d_in[1];
    const int*   batch = (const int*)d_in[2];
    const float* cW1   = (const float*)d_in[4];
    const float* cb1   = (const float*)d_in[5];
    const float* cbng  = (const float*)d_in[6];
    const float* cbnb  = (const float*)d_in[7];
    const float* cW2   = (const float*)d_in[8];
    const float* cb2   = (const float*)d_in[9];
    const float* bng   = (const float*)d_in[10];
    const float* bnb   = (const float*)d_in[11];
    const float* fcW   = (const float*)d_in[12];
    const float* fcb   = (const float*)d_in[13];

    char* base = (char*)d_ws;
    size_t off = 0;
    auto alloc = [&](size_t bytes) -> void* {
        void* p = base + off;
        off = (off + bytes + 255) & ~(size_t)255;
        return p;
    };
    unsigned*       zA     = (unsigned*)alloc((size_t)NN * 64 * 4);
    unsigned*       zB     = (unsigned*)alloc((size_t)NN * 64 * 4);   // also binned (NB*BUCKCAP*4 = 12.54MB)
    unsigned short* h8     = (unsigned short*)alloc((size_t)NN * 64 * 2);  // int8 codes of h
    unsigned short* Wtall  = (unsigned short*)alloc(8 * 16384 * 2);
    int*            ssort  = (int*)alloc((size_t)EE * 4);
    int*            rp     = (int*)alloc((NN + 1) * 4);
    int*            gstart = (int*)alloc((GG + 1) * 4);
    int*            bucketBase = (int*)alloc((NB + 1) * 4);
    // ---- contiguous zero region: bucketCur .. pooled slot 0 ----
    int*            bucketCur  = (int*)alloc(NB * 4);
    unsigned*       xmaxE  = (unsigned*)alloc(128 * 4);
    unsigned*       mstats = (unsigned*)alloc((size_t)LLAY * NSLOT * 256 * 4);
    float*          stats1 = (float*)alloc((size_t)LLAY * NSLOT * 256 * 4);
    float*          stats2 = (float*)alloc((size_t)LLAY * NSLOT * 256 * 4);
    float*          pooled = (float*)alloc((size_t)5 * GD * 4);
    // ------------------------------------------------------------
    float*          qD     = (float*)alloc(5 * 128 * 4);   // per-layer decode steps
    float*          qR     = (float*)alloc(128 * 4);       // layer-0 encode scale
    unsigned*       binned = (unsigned*)zB;   // alias: binned only used before layer loop

    int zwords = (int)(((char*)(pooled + GD) - (char*)bucketCur) / 4);  // incl. pooled[0] slot

    zero_k<<<(zwords + 255) / 256, 256, 0, stream>>>(bucketCur, zwords);
    wprep_k<<<512, 256, 0, stream>>>(cW1, cW2, Wtall);
    gsearch_k<<<3, 256, 0, stream>>>(batch, gstart);
    binA_k<<<(EE + BK_EDGES - 1) / BK_EDGES, 256, 0, stream>>>(ei, ei + EE, bucketCur, binned);
    bscan_k<<<1, 256, 0, stream>>>(bucketCur, bucketBase, rp);
    binB_k<<<NB, 1024, 0, stream>>>(binned, bucketCur, bucketBase, rp, ssort);
    xmax_k<<<512, 256, 0, stream>>>(x, xmaxE);
    qx_k<<<1, 128, 0, stream>>>(xmaxE, qD, qR);
    convxpool_k<<<4 * GG, 256, 0, stream>>>((const float2*)x, gstart, h8, qR, pooled);

    const int gemmGrid = 2 * ((NN + 127) / 128);   // 782 blocks (128-row tiles)
    const int SL = NSLOT * 256;
    for (int i = 0; i < LLAY; i++){
        agg_k<<<NN / 4, 256, 0, stream>>>(h8, rp, ssort,
                                          qD + i * 128, (i == 0) ? 128.f : 0.f, zA);
        gemm_k<0><<<gemmGrid, 256, 0, stream>>>(zA, Wtall + i * 16384, cb1 + i * 128,
                                                (unsigned short*)zB,
                                                nullptr, nullptr, nullptr,
                                                stats1 + (size_t)i * SL, nullptr, nullptr);
        gemm_k<1><<<gemmGrid, 256, 0, stream>>>(zB, Wtall + (4 + i) * 16384, cb2 + i * 128,
                                                (unsigned short*)zA,
                                                stats1 + (size_t)i * SL, cbng + i * 128, cbnb + i * 128,
                                                stats2 + (size_t)i * SL,
                                                pooled + (size_t)(i + 1) * GD,
                                                mstats + (size_t)i * SL);
        ewpool_k<<<4 * GG, 256, 0, stream>>>(zA, stats2 + (size_t)i * SL,
                                             bng + i * 128, bnb + i * 128,
                                             gstart, h8, mstats + (size_t)i * SL,
                                             qD + (i + 1) * 128,
                                             pooled + (size_t)(i + 1) * GD);
    }
    final_k<<<GG, 64, 0, stream>>>(pooled, fcW, fcb, (float*)d_out);
}

// Round 14
// 501.330 us; speedup vs baseline: 1.2066x; 1.0127x over previous
//
#include <hip/hip_runtime.h>

#define NN 50000
#define EE 1600000
#define DD 128
#define CC 10
#define LLAY 4
#define GG 512
#define GD (GG*DD)
#define NB 196           // ceil(NN/256) coarse buckets
#define BK_EDGES 1024    // edges per binA block (1563 blocks)
#define BUCKCAP 16000    // fixed binned region per bucket (expected 8192, >8 sigma safe)
#define NSUB 16          // src sub-tiles per node list (sorted gather window)
#define SUBW 3125        // 50000/16
#define WPAD 136         // Wl row stride in shorts (272B = 17 uint4: 2-way banks = free)
#define NSLOT 8          // replicated stat slots (atomic contention / 8)

static constexpr float BN_EPS = 1e-5f;
static constexpr float INV_N = 1.0f / (float)NN;

typedef __bf16 bf16x8 __attribute__((ext_vector_type(8)));
typedef float f32x4 __attribute__((ext_vector_type(4)));

static __device__ __forceinline__ float bflo(unsigned u){ return __uint_as_float(u << 16); }
static __device__ __forceinline__ float bfhi(unsigned u){ return __uint_as_float(u & 0xffff0000u); }
static __device__ __forceinline__ unsigned short f2bf(float f){
    unsigned u = __float_as_uint(f);
    return (unsigned short)((u + 0x7fffu + ((u >> 16) & 1u)) >> 16);   // RNE
}
static __device__ __forceinline__ unsigned packbf(float a, float b){
    return (unsigned)f2bf(a) | ((unsigned)f2bf(b) << 16);
}
// order-preserving float<->uint for atomicMax on signed floats (0 = identity)
static __device__ __forceinline__ unsigned encf(float f){
    unsigned b = __float_as_uint(f);
    return (b & 0x80000000u) ? ~b : (b | 0x80000000u);
}
static __device__ __forceinline__ float decf(unsigned e){
    unsigned b = (e & 0x80000000u) ? (e ^ 0x80000000u) : ~e;
    return __uint_as_float(b);
}
static __device__ __forceinline__ bf16x8 ldfrag(const unsigned short* p){
    union { uint4 u; bf16x8 b; } t; t.u = *(const uint4*)p; return t.b;
}
static __device__ __forceinline__ bf16x8 asfrag(uint4 u){
    union { uint4 u; bf16x8 b; } t; t.u = u; return t.b;
}

// ---------------- setup kernels ----------------

// merged zero + wprep + gsearch (independent work, blockIdx-range partitioned)
__global__ __launch_bounds__(256) void setup_k(int* __restrict__ zp, int zwords, int zblocks,
                                               const float* __restrict__ W1,
                                               const float* __restrict__ W2,
                                               unsigned short* __restrict__ Wtall,
                                               const int* __restrict__ batch,
                                               int* __restrict__ gstart){
    int blk = blockIdx.x, tid = threadIdx.x;
    if (blk < zblocks){
        int i = blk * 256 + tid;
        if (i < zwords) zp[i] = 0;
    } else if (blk < zblocks + 512){
        int idx = (blk - zblocks) * 256 + tid;        // < 8*16384
        int mat = idx >> 14; int rr = idx & 16383;
        int k = rr >> 7; int j = rr & 127;
        const float* Wsrc = (mat < 4) ? (W1 + mat * 16384) : (W2 + (mat - 4) * 16384);
        Wtall[mat * 16384 + j * 128 + k] = f2bf(Wsrc[k * 128 + j]);
    } else {
        int g = (blk - zblocks - 512) * 256 + tid;
        if (g <= GG){
            int lo = 0, hi = NN;
            while (lo < hi){ int mid = (lo + hi) >> 1; if (batch[mid] < g) lo = mid + 1; else hi = mid; }
            gstart[g] = lo;
        }
    }
}

// Pass A: bin edges into NB bucket regions with COALESCED writes (counting sort).
__global__ __launch_bounds__(256) void binA_k(const int* __restrict__ srcA,
                                              const int* __restrict__ dstA,
                                              int* __restrict__ bucketCur,
                                              unsigned* __restrict__ binned){
    __shared__ int cnt[256];           // per-bucket counts (NB <= 256)
    __shared__ int lb[256];            // scan buffer -> local exclusive base
    __shared__ int bas[NB];            // global base per bucket
    __shared__ int off[NB];            // running offset for LDS scatter
    __shared__ unsigned stage[BK_EDGES];
    __shared__ int tots;
    int tid = threadIdx.x;
    cnt[tid] = 0;
    if (tid < NB) off[tid] = 0;
    __syncthreads();
    int e0 = blockIdx.x * BK_EDGES;
    int myB[4]; unsigned myVal[4];
    #pragma unroll
    for (int k = 0; k < 4; k++){
        int e = e0 + tid + k * 256;
        bool v = (e < EE);
        int d = v ? dstA[e] : -1;
        int s = v ? srcA[e] : 0;
        myB[k] = v ? (d >> 8) : -1;
        myVal[k] = (unsigned)s | ((unsigned)(d & 255) << 17);   // src<2^17
        if (v) atomicAdd(&cnt[d >> 8], 1);
    }
    __syncthreads();
    int v = cnt[tid];
    lb[tid] = v; __syncthreads();
    for (int o = 1; o < 256; o <<= 1){                 // Hillis-Steele inclusive scan
        int x = 0; if (tid >= o) x = lb[tid - o];
        __syncthreads(); lb[tid] += x; __syncthreads();
    }
    int incl = lb[tid];
    if (tid == 255) tots = incl;
    __syncthreads();
    lb[tid] = incl - v;                                // exclusive base
    if (tid < NB && v > 0) bas[tid] = atomicAdd(&bucketCur[tid], v);
    __syncthreads();
    #pragma unroll
    for (int k = 0; k < 4; k++){
        int b = myB[k];
        if (b >= 0){
            int p = lb[b] + atomicAdd(&off[b], 1);
            stage[p] = myVal[k];
        }
    }
    __syncthreads();
    int tot = tots;
    for (int i = tid; i < tot; i += 256){
        int lo = 0, hi = NB - 1;                       // largest b with lb[b] <= i
        while (lo < hi){
            int mid = (lo + hi + 1) >> 1;
            if (lb[mid] <= i) lo = mid; else hi = mid - 1;
        }
        binned[lo * BUCKCAP + bas[lo] + (i - lb[lo])] = stage[i];
    }
}

// Pass B (1024 thr): per-bucket (node, 16-subtile) counts -> rp + src-sorted placement.
// bscan folded in: each block recomputes the 196-entry bucket prefix sum in LDS.
__global__ __launch_bounds__(1024) void binB_k(const unsigned* __restrict__ binned,
                                               const int* __restrict__ bucketCur,
                                               int* __restrict__ rp,
                                               int* __restrict__ ssort){
    __shared__ int c16[256 * NSUB];   // 16 KB
    __shared__ int b16[256 * NSUB];   // 16 KB
    __shared__ int nt[256];
    __shared__ int baseS;
    int b = blockIdx.x, tid = threadIdx.x;
    int nb0 = b * 256;
    int nmax = NN - nb0; if (nmax > 256) nmax = 256;
    // ---- local prefix over bucket counts (replaces bscan_k) ----
    if (tid < 256) nt[tid] = (tid < NB) ? bucketCur[tid] : 0;
    __syncthreads();
    for (int o = 1; o < 256; o <<= 1){
        int xv = 0;
        if (tid < 256 && tid >= o) xv = nt[tid - o];
        __syncthreads();
        if (tid < 256) nt[tid] += xv;
        __syncthreads();
    }
    if (tid == 0){
        baseS = nt[b] - bucketCur[b];   // exclusive prefix = this bucket's global base
        if (b == 0) rp[NN] = EE;
    }
    __syncthreads();
    int base = baseS;
    // ------------------------------------------------------------
    for (int i = tid; i < 256 * NSUB; i += 1024) c16[i] = 0;
    __syncthreads();
    int cntb = bucketCur[b];
    int src0 = b * BUCKCAP;
    for (int i = tid; i < cntb; i += 1024){
        unsigned u = binned[src0 + i];
        int src = (int)(u & 0x1FFFFu); int dl = (int)(u >> 17);
        atomicAdd(&c16[dl * NSUB + src / SUBW], 1);
    }
    __syncthreads();
    int cc[NSUB]; int tot = 0;
    if (tid < 256){
        #pragma unroll
        for (int k = 0; k < NSUB; k++){ cc[k] = c16[tid * NSUB + k]; tot += cc[k]; }
        nt[tid] = tot;
    }
    __syncthreads();
    for (int o = 1; o < 256; o <<= 1){
        int xv = 0;
        if (tid < 256 && tid >= o) xv = nt[tid - o];
        __syncthreads();
        if (tid < 256) nt[tid] += xv;
        __syncthreads();
    }
    if (tid < 256){
        int p = base + nt[tid] - tot;
        if (tid < nmax) rp[nb0 + tid] = p;
        int run = p;
        #pragma unroll
        for (int k = 0; k < NSUB; k++){ b16[tid * NSUB + k] = run; run += cc[k]; }
    }
    __syncthreads();
    for (int i = tid; i < 256 * NSUB; i += 1024) c16[i] = 0;
    __syncthreads();
    for (int i = tid; i < cntb; i += 1024){
        unsigned u = binned[src0 + i];
        int src = (int)(u & 0x1FFFFu); int dl = (int)(u >> 17);
        int t = src / SUBW;
        int pos = b16[dl * NSUB + t] + atomicAdd(&c16[dl * NSUB + t], 1);
        ssort[pos] = src;
    }
}

// column absmax of x (for layer-0 int8 scales). nonneg floats: raw-bit atomicMax ok.
__global__ __launch_bounds__(256) void xmax_k(const float* __restrict__ x,
                                              unsigned* __restrict__ xmaxE){
    __shared__ float sm[256];
    int tid = threadIdx.x;
    int col = tid & 127, rh = tid >> 7;
    float m = 0.f;
    for (int r = blockIdx.x * 2 + rh; r < NN; r += 1024)
        m = fmaxf(m, fabsf(x[r * 128 + col]));
    sm[tid] = m; __syncthreads();
    if (tid < 128){
        m = fmaxf(sm[tid], sm[tid + 128]);
        atomicMax(&xmaxE[col], __float_as_uint(m));
    }
}

// x (fp32) -> int8 codes (offset-128), fused with x-pooling.
// qx folded in: encode scales derived from xmaxE per thread; block 0 publishes qD0.
__global__ __launch_bounds__(256) void convxpool_k(const float2* __restrict__ x2,
                                                   const int* __restrict__ gstart,
                                                   unsigned short* __restrict__ h8u,
                                                   const unsigned* __restrict__ xmaxE,
                                                   float* __restrict__ qD0,
                                                   float* __restrict__ outp){
    __shared__ float sd[512];
    int b = blockIdx.x; int gid = b >> 2, chunk = b & 3;
    int tid = threadIdx.x; int c = tid & 63, rs = tid >> 6;
    int c2 = c * 2;
    float m0 = __uint_as_float(xmaxE[c2]);
    float m1 = __uint_as_float(xmaxE[c2 + 1]);
    float rvx = (m0 > 0.f) ? 127.f / m0 : 0.f;
    float rvy = (m1 > 0.f) ? 127.f / m1 : 0.f;
    if (b == 0 && rs == 0){
        qD0[c2]     = m0 * (1.f / 127.f);
        qD0[c2 + 1] = m1 * (1.f / 127.f);
    }
    int s = gstart[gid], e = gstart[gid + 1];
    float a0 = 0.f, a1 = 0.f;
    for (int n = s + chunk * 4 + rs; n < e; n += 16){
        float2 v = x2[n * 64 + c];
        int i0 = (int)rintf(v.x * rvx) + 128; i0 = min(max(i0, 0), 255);
        int i1 = (int)rintf(v.y * rvy) + 128; i1 = min(max(i1, 0), 255);
        h8u[n * 64 + c] = (unsigned short)(i0 | (i1 << 8));
        a0 += v.x; a1 += v.y;
    }
    sd[tid] = a0; sd[256 + tid] = a1; __syncthreads();
    if (tid < 64){
        float r0 = 0.f, r1 = 0.f;
        #pragma unroll
        for (int k2 = 0; k2 < 4; k2++){ r0 += sd[tid + 64 * k2]; r1 += sd[256 + tid + 64 * k2]; }
        atomicAdd(&outp[gid * 128 + 2 * tid], r0);
        atomicAdd(&outp[gid * 128 + 2 * tid + 1], r1);
    }
}

// ---------------- per-layer kernels ----------------

// z = Dc * (selfcode + sum of neighbor codes - off*(deg+1)).
// ushort payload: 64 lanes x 2 B = 128 B = one cache line per edge, wave-uniform
// row base (scalar-pipe indices), 16 loads in flight. Exact integer accumulate.
__global__ __launch_bounds__(256) void agg_k(const unsigned short* __restrict__ h8u,
                                             const int* __restrict__ rp,
                                             const int* __restrict__ ssort,
                                             const float* __restrict__ qD,
                                             float offv,
                                             unsigned* __restrict__ z32){
    int tid = threadIdx.x;
    int n = blockIdx.x * 4 + (tid >> 6);  // grid*4 == NN exactly
    int lane = tid & 63;
    int e  = __builtin_amdgcn_readfirstlane(rp[n]);
    int e1 = __builtin_amdgcn_readfirstlane(rp[n + 1]);
    int deg = e1 - e;
    unsigned su = (unsigned)h8u[n * 64 + lane];      // self code (same scale)
    unsigned acc0 = su & 0xFFu, acc1 = su >> 8;
    for (; e + 15 < e1; e += 16){
        int sA[16];
        #pragma unroll
        for (int k = 0; k < 16; k++) sA[k] = ssort[e + k];       // uniform -> scalar
        unsigned uA[16];
        #pragma unroll
        for (int k = 0; k < 16; k++) uA[k] = (unsigned)h8u[sA[k] * 64 + lane];
        #pragma unroll
        for (int k = 0; k < 16; k++){ acc0 += uA[k] & 0xFFu; acc1 += uA[k] >> 8; }
    }
    for (; e + 3 < e1; e += 4){
        int s0 = ssort[e], s1 = ssort[e + 1], s2 = ssort[e + 2], s3 = ssort[e + 3];
        unsigned u0 = (unsigned)h8u[s0 * 64 + lane];
        unsigned u1 = (unsigned)h8u[s1 * 64 + lane];
        unsigned u2 = (unsigned)h8u[s2 * 64 + lane];
        unsigned u3 = (unsigned)h8u[s3 * 64 + lane];
        acc0 += (u0 & 0xFFu) + (u1 & 0xFFu) + (u2 & 0xFFu) + (u3 & 0xFFu);
        acc1 += (u0 >> 8) + (u1 >> 8) + (u2 >> 8) + (u3 >> 8);
    }
    for (; e < e1; ++e){
        unsigned u0 = (unsigned)h8u[ssort[e] * 64 + lane];
        acc0 += u0 & 0xFFu; acc1 += u0 >> 8;
    }
    float2 qd = ((const float2*)qD)[lane];
    float degoff = offv * (float)(deg + 1);          // self included
    float z0 = qd.x * ((float)acc0 - degoff);
    float z1 = qd.y * ((float)acc1 - degoff);
    z32[n * 64 + lane] = packbf(z0, z1);
}

// C[N, 64-col slice] = opt_relu_bn(A[N,128]) @ W-slice + bias, bf16 MFMA 16x16x32.
// 128-row x 64-col tile (782 blocks). Stats go to one of NSLOT replicated
// 256-word slots (slot = (blockIdx>>1)&7) -> atomic contention /8.
template<int TR>
__global__ __launch_bounds__(256) void gemm_k(const unsigned* __restrict__ A32,
                                              const unsigned short* __restrict__ Wtg,
                                              const float* __restrict__ bias,
                                              unsigned short* __restrict__ Cst,
                                              const float* __restrict__ stats,
                                              const float* __restrict__ gma,
                                              const float* __restrict__ bta,
                                              float* __restrict__ ostats,
                                              float* __restrict__ zpool,
                                              unsigned* __restrict__ mst){
    __shared__ __align__(16) unsigned short Wl[64 * WPAD];  // 17.4KB, [j][k] padded
    __shared__ float sred[1024];
    __shared__ __align__(16) float sl[128], tl[128];
    int tid = threadIdx.x;
    int slice = blockIdx.x & 1;
    int tileb = blockIdx.x >> 1;
    int slot = tileb & (NSLOT - 1);

    // ---- issue A-loads first: their ~L3 latency overlaps W-staging + barrier ----
    int wv = tid >> 6, lane = tid & 63;
    int rowbase = tileb * 128 + wv * 32;
    int r0 = rowbase + (lane & 15);
    int r1 = r0 + 16;
    int kd = (lane >> 4) * 4;       // dword offset within 16-dword k-group
    uint4 va[4], vb[4];
    #pragma unroll
    for (int ks = 0; ks < 4; ks++){
        va[ks] = (r0 < NN) ? *(const uint4*)(A32 + r0 * 64 + ks * 16 + kd) : make_uint4(0,0,0,0);
        vb[ks] = (r1 < NN) ? *(const uint4*)(A32 + r1 * 64 + ks * 16 + kd) : make_uint4(0,0,0,0);
    }

    if (zpool && blockIdx.x < 256) zpool[blockIdx.x * 256 + tid] = 0.f;
    {   // stage 64 W^T rows [slice*64, slice*64+64): each row = 16 uint4, padded to 17
        const uint4* src = (const uint4*)(Wtg + slice * 64 * 128);
        uint4* dst = (uint4*)Wl;
        #pragma unroll
        for (int i = 0; i < 4; i++){
            int idx = tid + 256 * i;            // 0..1023
            int row = idx >> 4, c16 = idx & 15; // 64 rows x 16 uint4
            dst[row * (WPAD / 8) + c16] = src[idx];
        }
    }
    if (TR && tid < 128){
        float sum1 = 0.f, sum2 = 0.f;
        #pragma unroll
        for (int s8 = 0; s8 < NSLOT; s8++){
            sum1 += stats[s8 * 256 + tid];
            sum2 += stats[s8 * 256 + 128 + tid];
        }
        float mean = sum1 * INV_N;
        float q    = sum2 * INV_N;
        float inv  = rsqrtf(q - mean * mean + BN_EPS);
        float s    = gma[tid] * inv;
        sl[tid] = s; tl[tid] = bta[tid] - mean * s;
    }
    __syncthreads();

    if (TR){
        #pragma unroll
        for (int ks = 0; ks < 4; ks++){
            int q = ks * 8 + (lane >> 4) * 2;       // float4 index: k0/4
            float4 sA = ((const float4*)sl)[q], sB = ((const float4*)sl)[q + 1];
            float4 tA = ((const float4*)tl)[q], tB = ((const float4*)tl)[q + 1];
            float fs[8] = {sA.x, sA.y, sA.z, sA.w, sB.x, sB.y, sB.z, sB.w};
            float ft[8] = {tA.x, tA.y, tA.z, tA.w, tB.x, tB.y, tB.z, tB.w};
            unsigned* pa = (unsigned*)&va[ks];
            unsigned* pb = (unsigned*)&vb[ks];
            #pragma unroll
            for (int c = 0; c < 4; c++){
                float f0 = fmaxf(bflo(pa[c]) * fs[2*c] + ft[2*c], 0.f);
                float f1 = fmaxf(bfhi(pa[c]) * fs[2*c+1] + ft[2*c+1], 0.f);
                pa[c] = packbf(f0, f1);
                f0 = fmaxf(bflo(pb[c]) * fs[2*c] + ft[2*c], 0.f);
                f1 = fmaxf(bfhi(pb[c]) * fs[2*c+1] + ft[2*c+1], 0.f);
                pb[c] = packbf(f0, f1);
            }
        }
    }

    f32x4 acc[2][4];
    #pragma unroll
    for (int a = 0; a < 2; a++)
        #pragma unroll
        for (int b = 0; b < 4; b++) acc[a][b] = (f32x4){0.f, 0.f, 0.f, 0.f};

    #pragma unroll
    for (int ks = 0; ks < 4; ks++){
        int wk = ks * 32 + (lane >> 4) * 8;
        bf16x8 a0 = asfrag(va[ks]);
        bf16x8 a1 = asfrag(vb[ks]);
        #pragma unroll
        for (int ct = 0; ct < 4; ++ct){
            bf16x8 b = ldfrag(&Wl[(ct * 16 + (lane & 15)) * WPAD + wk]);
            acc[0][ct] = __builtin_amdgcn_mfma_f32_16x16x32_bf16(a0, b, acc[0][ct], 0, 0, 0);
            acc[1][ct] = __builtin_amdgcn_mfma_f32_16x16x32_bf16(a1, b, acc[1][ct], 0, 0, 0);
        }
    }

    // epilogue: C/D layout col=lane&15, row=(lane>>4)*4+reg. Store + column stats.
    int cl = lane & 15, rq = lane >> 4;
    float colS[4], colQ[4];
    #pragma unroll
    for (int ct = 0; ct < 4; ++ct){
        int col = slice * 64 + ct * 16 + cl;
        float bv = bias[col];
        float ps = 0.f, pq = 0.f;
        float vx = -3.4e38f, vn = -3.4e38f;
        #pragma unroll
        for (int rt = 0; rt < 2; ++rt){
            #pragma unroll
            for (int rr2 = 0; rr2 < 4; ++rr2){
                int grow = rowbase + rt * 16 + rq * 4 + rr2;
                if (grow < NN){
                    float val = acc[rt][ct][rr2] + bv;
                    Cst[grow * 128 + col] = f2bf(val);
                    ps += val; pq += val * val;
                    if (TR){ vx = fmaxf(vx, val); vn = fmaxf(vn, -val); }
                }
            }
        }
        ps += __shfl_xor(ps, 16); pq += __shfl_xor(pq, 16);
        ps += __shfl_xor(ps, 32); pq += __shfl_xor(pq, 32);
        colS[ct] = ps; colQ[ct] = pq;
        if (TR){
            vx = fmaxf(vx, __shfl_xor(vx, 16)); vx = fmaxf(vx, __shfl_xor(vx, 32));
            vn = fmaxf(vn, __shfl_xor(vn, 16)); vn = fmaxf(vn, __shfl_xor(vn, 32));
            if (rq == 0){
                sred[512 + wv * 64 + ct * 16 + cl] = vx;
                sred[768 + wv * 64 + ct * 16 + cl] = vn;
            }
        }
    }
    if (rq == 0){
        #pragma unroll
        for (int ct = 0; ct < 4; ++ct){
            sred[wv * 64 + ct * 16 + cl]       = colS[ct];
            sred[256 + wv * 64 + ct * 16 + cl] = colQ[ct];
        }
    }
    __syncthreads();
    if (tid < 64){
        float s1 = sred[tid] + sred[64 + tid] + sred[128 + tid] + sred[192 + tid];
        float s2 = sred[256 + tid] + sred[320 + tid] + sred[384 + tid] + sred[448 + tid];
        atomicAdd(&ostats[slot * 256 + slice * 64 + tid], s1);
        atomicAdd(&ostats[slot * 256 + 128 + slice * 64 + tid], s2);
        if (TR){
            float mx = fmaxf(fmaxf(sred[512 + tid], sred[576 + tid]),
                             fmaxf(sred[640 + tid], sred[704 + tid]));
            float mn = fmaxf(fmaxf(sred[768 + tid], sred[832 + tid]),
                             fmaxf(sred[896 + tid], sred[960 + tid]));
            atomicMax(&mst[slot * 256 + slice * 64 + tid], encf(mx));
            atomicMax(&mst[slot * 256 + 128 + slice * 64 + tid], encf(mn));
        }
    }
}

// h = relu(bn(z)) -> int8 codes only, fused with pooling. Consumes 8-slot stats
// (sum) and 8-slot mst (max of order-preserving encodings). Block 0 publishes qDn.
__global__ __launch_bounds__(256) void ewpool_k(const unsigned* __restrict__ z32,
                                                const float* __restrict__ stats,
                                                const float* __restrict__ g,
                                                const float* __restrict__ b,
                                                const int* __restrict__ gstart,
                                                unsigned short* __restrict__ h8u,
                                                const unsigned* __restrict__ mst,
                                                float* __restrict__ qDn,
                                                float* __restrict__ outp){
    __shared__ float sd[512];
    int blk = blockIdx.x; int gid = blk >> 2, chunk = blk & 3;
    int tid = threadIdx.x;
    int c = tid & 63, rs = tid >> 6;
    int c2 = c * 2;
    float sm0 = 0.f, sq0 = 0.f, sm1 = 0.f, sq1 = 0.f;
    unsigned ex0 = 0u, en0 = 0u, ex1 = 0u, en1 = 0u;
    #pragma unroll
    for (int s8 = 0; s8 < NSLOT; s8++){
        sm0 += stats[s8 * 256 + c2];       sq0 += stats[s8 * 256 + 128 + c2];
        sm1 += stats[s8 * 256 + c2 + 1];   sq1 += stats[s8 * 256 + 129 + c2];
        ex0 = max(ex0, mst[s8 * 256 + c2]);       en0 = max(en0, mst[s8 * 256 + 128 + c2]);
        ex1 = max(ex1, mst[s8 * 256 + c2 + 1]);   en1 = max(en1, mst[s8 * 256 + 129 + c2]);
    }
    float m0 = sm0 * INV_N, q0 = sq0 * INV_N;
    float inv0 = rsqrtf(q0 - m0 * m0 + BN_EPS);
    float s0 = g[c2] * inv0, t0 = b[c2] - m0 * s0;
    float m1 = sm1 * INV_N, q1 = sq1 * INV_N;
    float inv1 = rsqrtf(q1 - m1 * m1 + BN_EPS);
    float s1 = g[c2 + 1] * inv1, t1 = b[c2 + 1] - m1 * s1;
    // exact column hmax through monotone affine bn + relu
    float zx0 = decf(ex0), zn0 = -decf(en0);
    float zx1 = decf(ex1), zn1 = -decf(en1);
    float hm0 = fmaxf(fmaxf(s0 * zx0 + t0, s0 * zn0 + t0), 0.f);
    float hm1 = fmaxf(fmaxf(s1 * zx1 + t1, s1 * zn1 + t1), 0.f);
    float r80 = (hm0 > 0.f) ? 255.f / hm0 : 0.f;
    float r81 = (hm1 > 0.f) ? 255.f / hm1 : 0.f;
    if (blk == 0 && rs == 0){
        qDn[c2]     = hm0 * (1.f / 255.f);
        qDn[c2 + 1] = hm1 * (1.f / 255.f);
    }
    int s = gstart[gid], e = gstart[gid + 1];
    float a0 = 0.f, a1 = 0.f;
    int n = s + chunk * 4 + rs;
    for (; n + 16 < e; n += 32){
        unsigned u0 = z32[n * 64 + c];
        unsigned u1 = z32[(n + 16) * 64 + c];
        float f0 = fmaxf(bflo(u0) * s0 + t0, 0.f);
        float f1 = fmaxf(bfhi(u0) * s1 + t1, 0.f);
        unsigned cu0 = (unsigned)(f0 * r80 + 0.5f); if (cu0 > 255u) cu0 = 255u;
        unsigned cu1 = (unsigned)(f1 * r81 + 0.5f); if (cu1 > 255u) cu1 = 255u;
        h8u[n * 64 + c] = (unsigned short)(cu0 | (cu1 << 8));
        a0 += f0; a1 += f1;
        f0 = fmaxf(bflo(u1) * s0 + t0, 0.f);
        f1 = fmaxf(bfhi(u1) * s1 + t1, 0.f);
        cu0 = (unsigned)(f0 * r80 + 0.5f); if (cu0 > 255u) cu0 = 255u;
        cu1 = (unsigned)(f1 * r81 + 0.5f); if (cu1 > 255u) cu1 = 255u;
        h8u[(n + 16) * 64 + c] = (unsigned short)(cu0 | (cu1 << 8));
        a0 += f0; a1 += f1;
    }
    for (; n < e; n += 16){
        unsigned u = z32[n * 64 + c];
        float f0 = fmaxf(bflo(u) * s0 + t0, 0.f);
        float f1 = fmaxf(bfhi(u) * s1 + t1, 0.f);
        unsigned cu0 = (unsigned)(f0 * r80 + 0.5f); if (cu0 > 255u) cu0 = 255u;
        unsigned cu1 = (unsigned)(f1 * r81 + 0.5f); if (cu1 > 255u) cu1 = 255u;
        h8u[n * 64 + c] = (unsigned short)(cu0 | (cu1 << 8));
        a0 += f0; a1 += f1;
    }
    sd[tid] = a0; sd[256 + tid] = a1; __syncthreads();
    if (tid < 64){
        float r0 = 0.f, r1 = 0.f;
        #pragma unroll
        for (int k2 = 0; k2 < 4; k2++){ r0 += sd[tid + 64 * k2]; r1 += sd[256 + tid + 64 * k2]; }
        atomicAdd(&outp[gid * 128 + 2 * tid], r0);
        atomicAdd(&outp[gid * 128 + 2 * tid + 1], r1);
    }
}

// logits = sum_i pooled_i @ fcW_i + fcb_i ; out = log_softmax(logits)
__global__ __launch_bounds__(64) void final_k(const float* __restrict__ pooled,
                                              const float* __restrict__ fcW,
                                              const float* __restrict__ fcb,
                                              float* __restrict__ out){
    int g = blockIdx.x, l = threadIdx.x;
    float p0[5], p1[5];
    #pragma unroll
    for (int i = 0; i < 5; i++){
        p0[i] = pooled[i * GD + g * 128 + l];
        p1[i] = pooled[i * GD + g * 128 + 64 + l];
    }
    float lg[10];
    #pragma unroll
    for (int c2 = 0; c2 < 10; c2++){
        float s = 0;
        #pragma unroll
        for (int i = 0; i < 5; i++){
            s += p0[i] * fcW[(i * 128 + l) * 10 + c2];
            s += p1[i] * fcW[(i * 128 + 64 + l) * 10 + c2];
        }
        #pragma unroll
        for (int off = 32; off >= 1; off >>= 1) s += __shfl_down(s, off);
        lg[c2] = s;
    }
    if (l == 0){
        #pragma unroll
        for (int c2 = 0; c2 < 10; c2++){
            float bs = 0;
            #pragma unroll
            for (int i = 0; i < 5; i++) bs += fcb[i * 10 + c2];
            lg[c2] += bs;
        }
        float mx = lg[0];
        #pragma unroll
        for (int c2 = 1; c2 < 10; c2++) mx = fmaxf(mx, lg[c2]);
        float se = 0;
        #pragma unroll
        for (int c2 = 0; c2 < 10; c2++) se += expf(lg[c2] - mx);
        float lse = mx + logf(se);
        #pragma unroll
        for (int c2 = 0; c2 < 10; c2++) out[g * 10 + c2] = lg[c2] - lse;
    }
}

// ---------------- launch ----------------

extern "C" void kernel_launch(void* const* d_in, const int* in_sizes, int n_in,
                              void* d_out, int out_size, void* d_ws, size_t ws_size,
                              hipStream_t stream){
    (void)in_sizes; (void)n_in; (void)out_size; (void)ws_size;
    const float* x     = (const float*)d_in[0];
    const int*   ei    = (const int*)d_in[1];
    const int*   batch = (const int*)d_in[2];
    const float* cW1   = (const float*)d_in[4];
    const float* cb1   = (const float*)d_in[5];
    const float* cbng  = (const float*)d_in[6];
    const float* cbnb  = (const float*)d_in[7];
    const float* cW2   = (const float*)d_in[8];
    const float* cb2   = (const float*)d_in[9];
    const float* bng   = (const float*)d_in[10];
    const float* bnb   = (const float*)d_in[11];
    const float* fcW   = (const float*)d_in[12];
    const float* fcb   = (const float*)d_in[13];

    char* base = (char*)d_ws;
    size_t off = 0;
    auto alloc = [&](size_t bytes) -> void* {
        void* p = base + off;
        off = (off + bytes + 255) & ~(size_t)255;
        return p;
    };
    unsigned*       zA     = (unsigned*)alloc((size_t)NN * 64 * 4);
    unsigned*       zB     = (unsigned*)alloc((size_t)NN * 64 * 4);   // also binned (NB*BUCKCAP*4 = 12.54MB)
    unsigned short* h8     = (unsigned short*)alloc((size_t)NN * 64 * 2);  // int8 codes of h
    unsigned short* Wtall  = (unsigned short*)alloc(8 * 16384 * 2);
    int*            ssort  = (int*)alloc((size_t)EE * 4);
    int*            rp     = (int*)alloc((NN + 1) * 4);
    int*            gstart = (int*)alloc((GG + 1) * 4);
    // ---- contiguous zero region: bucketCur .. pooled slot 0 ----
    int*            bucketCur  = (int*)alloc(NB * 4);
    unsigned*       xmaxE  = (unsigned*)alloc(128 * 4);
    unsigned*       mstats = (unsigned*)alloc((size_t)LLAY * NSLOT * 256 * 4);
    float*          stats1 = (float*)alloc((size_t)LLAY * NSLOT * 256 * 4);
    float*          stats2 = (float*)alloc((size_t)LLAY * NSLOT * 256 * 4);
    float*          pooled = (float*)alloc((size_t)5 * GD * 4);
    // ------------------------------------------------------------
    float*          qD     = (float*)alloc(5 * 128 * 4);   // per-layer decode steps
    unsigned*       binned = (unsigned*)zB;   // alias: binned only used before layer loop

    int zwords = (int)(((char*)(pooled + GD) - (char*)bucketCur) / 4);  // incl. pooled[0] slot
    int zblocks = (zwords + 255) / 256;

    setup_k<<<zblocks + 515, 256, 0, stream>>>(bucketCur, zwords, zblocks,
                                               cW1, cW2, Wtall, batch, gstart);
    binA_k<<<(EE + BK_EDGES - 1) / BK_EDGES, 256, 0, stream>>>(ei, ei + EE, bucketCur, binned);
    binB_k<<<NB, 1024, 0, stream>>>(binned, bucketCur, rp, ssort);
    xmax_k<<<512, 256, 0, stream>>>(x, xmaxE);
    convxpool_k<<<4 * GG, 256, 0, stream>>>((const float2*)x, gstart, h8, xmaxE, qD, pooled);

    const int gemmGrid = 2 * ((NN + 127) / 128);   // 782 blocks (128-row tiles)
    const int SL = NSLOT * 256;
    for (int i = 0; i < LLAY; i++){
        agg_k<<<NN / 4, 256, 0, stream>>>(h8, rp, ssort,
                                          qD + i * 128, (i == 0) ? 128.f : 0.f, zA);
        gemm_k<0><<<gemmGrid, 256, 0, stream>>>(zA, Wtall + i * 16384, cb1 + i * 128,
                                                (unsigned short*)zB,
                                                nullptr, nullptr, nullptr,
                                                stats1 + (size_t)i * SL, nullptr, nullptr);
        gemm_k<1><<<gemmGrid, 256, 0, stream>>>(zB, Wtall + (4 + i) * 16384, cb2 + i * 128,
                                                (unsigned short*)zA,
                                                stats1 + (size_t)i * SL, cbng + i * 128, cbnb + i * 128,
                                                stats2 + (size_t)i * SL,
                                                pooled + (size_t)(i + 1) * GD,
                                                mstats + (size_t)i * SL);
        ewpool_k<<<4 * GG, 256, 0, stream>>>(zA, stats2 + (size_t)i * SL,
                                             bng + i * 128, bnb + i * 128,
                                             gstart, h8, mstats + (size_t)i * SL,
                                             qD + (i + 1) * 128,
                                             pooled + (size_t)(i + 1) * GD);
    }
    final_k<<<GG, 64, 0, stream>>>(pooled, fcW, fcb, (float*)d_out);
}